// Round 9
// baseline (1138.162 us; speedup 1.0000x reference)
//
#include <hip/hip_runtime.h>
#include <hip/hip_bf16.h>
#include <stdint.h>

#define NB 16
#define NPTS 4096
#define NS 1024
#define NK 32
#define NT_COLS (NB*NS*NK)   // 524288 columns (b*NS+s)*NK + k
#define NBUCK 64             // stat-accumulator buckets

typedef __hip_bfloat16 bf16;
typedef __attribute__((ext_vector_type(8))) short short8;   // 8 bf16 (4 VGPRs)
typedef __attribute__((ext_vector_type(4))) float floatx4;  // MFMA C/D

__device__ __forceinline__ unsigned short f2bf_bits(float v) {
  bf16 b = __float2bfloat16(v);
  return *(unsigned short*)&b;
}

__global__ void k_zero(float* __restrict__ p) {
  p[blockIdx.x*256 + threadIdx.x] = 0.f;
}

// DPP-shifted fmax (verified gfx950, R5/R7/R8). Inactive/OOB src lanes keep old=x.
template<int CTRL, int RM, int BM>
__device__ __forceinline__ float fmax_dpp(float x) {
  int o = __builtin_amdgcn_update_dpp(__float_as_int(x), __float_as_int(x),
                                      CTRL, RM, BM, false);
  return fmaxf(x, __int_as_float(o));
}
// DPP-shifted add with zero-fill; 4-step chain sums 16-lane row onto lane 15.
template<int CTRL>
__device__ __forceinline__ float add_dpp(float x) {
  int o = __builtin_amdgcn_update_dpp(0, __float_as_int(x), CTRL, 0xF, 0xF, true);
  return __fadd_rn(x, __int_as_float(o));
}

// ---------------- FPS: 256 thr; short-serial-chain iteration ----------------
// np-exact: (x-c)^2 elementwise, sequential 3-term sum, no FMA; first-occur
// argmax at all levels (in-lane smallest j via descending chain, in-wave
// lowest lane via ctz(ballot), cross-wave strict > in ascending wave order).
// Exchange carries winner COORDS (prefetched gather, latency hidden under the
// DPP chain) so no dependent xs[cur] fetch sits on the post-barrier path.
__global__ __launch_bounds__(256) void k_fps(const float* __restrict__ xyz,
                                             float* __restrict__ newxyz,
                                             float* __restrict__ out0) {
  __shared__ float4 pts4[NPTS];             // (x,y,z,0) per point
  __shared__ float  selx[NS], sely[NS], selz[NS];
  __shared__ float4 pair[2][4];             // (M, x, y, z) per wave, dbuf
  const int b = blockIdx.x;
  const int t = threadIdx.x;
  const float* p = xyz + (size_t)b * 3 * NPTS;
  for (int i = t; i < NPTS; i += 256)
    pts4[i] = make_float4(p[i], p[NPTS + i], p[2*NPTS + i], 0.f);
  __syncthreads();
  float px[16], py[16], pz[16], dist[16];
  const int p0 = t * 16;                    // lane/wave-contiguous ownership
  #pragma unroll
  for (int j = 0; j < 16; ++j) {
    float4 q = pts4[p0+j];
    px[j]=q.x; py[j]=q.y; pz[j]=q.z; dist[j]=1e10f;
  }
  const int lane = t & 63, wv = t >> 6;
  float4 c0v = pts4[0];
  float cx = c0v.x, cy = c0v.y, cz = c0v.z;
  for (int i = 0; i < NS; ++i) {
    if (t == 0) { selx[i] = cx; sely[i] = cy; selz[i] = cz; }
    if (i == NS-1) break;
    float bv = -1.0f;
    #pragma unroll
    for (int j = 0; j < 16; j += 2) {
      float dx0 = __fsub_rn(px[j],   cx), dx1 = __fsub_rn(px[j+1], cx);
      float dy0 = __fsub_rn(py[j],   cy), dy1 = __fsub_rn(py[j+1], cy);
      float dz0 = __fsub_rn(pz[j],   cz), dz1 = __fsub_rn(pz[j+1], cz);
      float d0 = __fadd_rn(__fadd_rn(__fmul_rn(dx0,dx0), __fmul_rn(dy0,dy0)), __fmul_rn(dz0,dz0));
      float d1 = __fadd_rn(__fadd_rn(__fmul_rn(dx1,dx1), __fmul_rn(dy1,dy1)), __fmul_rn(dz1,dz1));
      float nd0 = fminf(dist[j],   d0);
      float nd1 = fminf(dist[j+1], d1);
      dist[j] = nd0; dist[j+1] = nd1;
      bv = fmaxf(bv, fmaxf(nd0, nd1));      // -> v_max3_f32
    }
    // recover smallest j with dist[j]==bv (descending: last match wins)
    int bi = p0;
    #pragma unroll
    for (int j = 15; j >= 0; --j)
      bi = (dist[j] == bv) ? (p0 + j) : bi;
    // prefetch candidate coords; latency hides under DPP+ballot below
    float4 cand = pts4[bi];
    // wave64 max via DPP chain (converges to lane 63)
    float x = bv;
    x = fmax_dpp<0x111,0xF,0xF>(x);   // row_shr:1
    x = fmax_dpp<0x112,0xF,0xF>(x);   // row_shr:2
    x = fmax_dpp<0x114,0xF,0xF>(x);   // row_shr:4
    x = fmax_dpp<0x118,0xF,0xF>(x);   // row_shr:8
    x = fmax_dpp<0x142,0xA,0xF>(x);   // row_bcast:15 -> rows 1,3
    x = fmax_dpp<0x143,0xC,0xF>(x);   // row_bcast:31 -> rows 2,3
    float M = __int_as_float(__builtin_amdgcn_readlane(__float_as_int(x), 63));
    unsigned long long mk = __ballot(bv == M);
    int sl = (int)__builtin_ctzll(mk);
    if (lane == sl) pair[i & 1][wv] = make_float4(M, cand.x, cand.y, cand.z);
    __syncthreads();
    float4 q0 = pair[i & 1][0];
    float4 q1 = pair[i & 1][1];
    float4 q2 = pair[i & 1][2];
    float4 q3 = pair[i & 1][3];
    float bestv = q0.x; float wx = q0.y, wy = q0.z, wz = q0.w;
    if (q1.x > bestv) { bestv = q1.x; wx = q1.y; wy = q1.z; wz = q1.w; }
    if (q2.x > bestv) { bestv = q2.x; wx = q2.y; wy = q2.z; wz = q2.w; }
    if (q3.x > bestv) { bestv = q3.x; wx = q3.y; wy = q3.z; wz = q3.w; }
    cx = wx; cy = wy; cz = wz;              // uniform across block
  }
  __syncthreads();
  for (int i = t; i < NS; i += 256) {
    float vx = selx[i], vy = sely[i], vz = selz[i];
    size_t q = (size_t)b*3*NS + i;
    out0[q] = vx; out0[q + NS] = vy; out0[q + 2*NS] = vz;   // bit-exact copies
    size_t o = (size_t)(b*NS + i)*3;
    newxyz[o] = vx; newxyz[o+1] = vy; newxyz[o+2] = vz;
  }
}

// ---------------- Ball query: one wave per query ----------------------------
__global__ __launch_bounds__(256) void k_ballq(const float* __restrict__ xyz,
                                               const float* __restrict__ newxyz,
                                               int* __restrict__ idx) {
  const int gw = (blockIdx.x * 256 + threadIdx.x) >> 6;
  const int lane = threadIdx.x & 63;
  const int b = gw >> 10;
  const int s = gw & (NS-1);
  const float* xb = xyz + (size_t)b * 3 * NPTS;
  const size_t nq = (size_t)(b*NS + s)*3;
  const float nx = newxyz[nq], ny = newxyz[nq+1], nz = newxyz[nq+2];
  const float sn = __fadd_rn(__fadd_rn(__fmul_rn(nx,nx), __fmul_rn(ny,ny)), __fmul_rn(nz,nz));
  const float R2 = (float)(0.2*0.2);
  int* out = idx + (size_t)gw * NK;
  int cnt = 0, first = 0;
  for (int c0 = 0; c0 < NPTS; c0 += 64) {
    int n = c0 + lane;
    float x = xb[n], y = xb[NPTS+n], z = xb[2*NPTS+n];
    float sx = __fadd_rn(__fadd_rn(__fmul_rn(x,x), __fmul_rn(y,y)), __fmul_rn(z,z));
    float dt = __fadd_rn(__fadd_rn(__fmul_rn(nx,x), __fmul_rn(ny,y)), __fmul_rn(nz,z));
    float sqr = __fsub_rn(__fadd_rn(sn, sx), __fmul_rn(2.0f, dt));
    bool inr = (sqr <= R2);
    unsigned long long m = __ballot(inr);
    if (m != 0ull) {
      if (cnt == 0) first = c0 + (int)__builtin_ctzll(m);
      int rank = __popcll(m & ((1ull << lane) - 1ull));
      int pos = cnt + rank;
      if (inr && pos < NK) out[pos] = n;
      cnt += __popcll(m);
      if (cnt >= NK) break;
    }
  }
  int tot = cnt < NK ? cnt : NK;
  if (lane >= tot && lane < NK) out[lane] = first;
}

// ---------------- Layer 1: gather + 6->64 conv -----------------------------
__global__ __launch_bounds__(256) void k_layer1(const float* __restrict__ xyz,
                                                const float* __restrict__ feat,
                                                const float* __restrict__ newxyz,
                                                const int* __restrict__ idx,
                                                const float* __restrict__ w0,
                                                const float* __restrict__ b0,
                                                bf16* __restrict__ x1) {
  __shared__ float w[64*6];
  __shared__ float bias[64];
  for (int i = threadIdx.x; i < 64*6; i += 256) w[i] = w0[i];
  if (threadIdx.x < 64) bias[threadIdx.x] = b0[threadIdx.x];
  __syncthreads();
  const int col = blockIdx.x * 256 + threadIdx.x;
  const int bs = col >> 5;
  const int b  = bs >> 10;
  const int n  = idx[col];
  const float* xb = xyz  + (size_t)b*3*NPTS;
  const float* fb = feat + (size_t)b*3*NPTS;
  float in[6];
  in[0] = __fsub_rn(xb[n],        newxyz[(size_t)bs*3]);
  in[1] = __fsub_rn(xb[NPTS+n],   newxyz[(size_t)bs*3+1]);
  in[2] = __fsub_rn(xb[2*NPTS+n], newxyz[(size_t)bs*3+2]);
  in[3] = fb[n];
  in[4] = fb[NPTS+n];
  in[5] = fb[2*NPTS+n];
  #pragma unroll
  for (int o = 0; o < 64; ++o) {
    float acc = bias[o];
    #pragma unroll
    for (int c = 0; c < 6; ++c) acc = fmaf(in[c], w[o*6+c], acc);
    x1[(size_t)o*NT_COLS + col] = __float2bfloat16(acc);
  }
}

// ---------------- Per-channel sum/sumsq for x1 (bucketed accum) -------------
__global__ __launch_bounds__(256) void k_stats(const bf16* __restrict__ x,
                                               float* __restrict__ accum, int C) {
  const int o = blockIdx.x >> 5;
  const int chunk = blockIdx.x & 31;
  const uint4* p = (const uint4*)(x + (size_t)o*NT_COLS + (size_t)chunk*16384);
  float s = 0.f, ss = 0.f;
  #pragma unroll
  for (int it = 0; it < 8; ++it) {
    uint4 u = p[threadIdx.x + it*256];
    uint32_t wr[4] = {u.x, u.y, u.z, u.w};
    #pragma unroll
    for (int q = 0; q < 4; ++q) {
      float a  = __uint_as_float(wr[q] << 16);
      float bq = __uint_as_float(wr[q] & 0xffff0000u);
      s += a;  ss = fmaf(a, a, ss);
      s += bq; ss = fmaf(bq, bq, ss);
    }
  }
  #pragma unroll
  for (int off = 32; off; off >>= 1) { s += __shfl_xor(s, off); ss += __shfl_xor(ss, off); }
  __shared__ float ls[4], lss[4];
  const int lane = threadIdx.x & 63, wv = threadIdx.x >> 6;
  if (lane == 0) { ls[wv] = s; lss[wv] = ss; }
  __syncthreads();
  if (threadIdx.x == 0) {
    float* dst = accum + (size_t)(blockIdx.x & (NBUCK-1))*(2*C);
    atomicAdd(&dst[o],     (ls[0]+ls[1])+(ls[2]+ls[3]));
    atomicAdd(&dst[C + o], (lss[0]+lss[1])+(lss[2]+lss[3]));
  }
}

// ---------------- finalize: sum buckets -> sc/sh ---------------------------
__global__ void k_finalize(const float* __restrict__ accum,
                           const float* __restrict__ g, const float* __restrict__ beta,
                           float* __restrict__ scsh, int C) {
  int o = threadIdx.x;
  if (o < C) {
    float s = 0.f, ss = 0.f;
    for (int bkt = 0; bkt < NBUCK; ++bkt) {
      s  += accum[(size_t)bkt*(2*C) + o];
      ss += accum[(size_t)bkt*(2*C) + C + o];
    }
    const float n = (float)NT_COLS;
    float mu  = s / n;
    float var = ss / n - mu*mu;
    if (var < 0.f) var = 0.f;
    float rs = rsqrtf(var + 1e-5f);
    float sc = g[o] * rs;
    scsh[o]   = sc;
    scsh[C+o] = beta[o] - mu * sc;
  }
}

// ---------------- Layers 2/3: MFMA GEMM + fused stats (+ fused max) --------
#define XT_STRIDE 72   // bf16 elems; 144 B row -> b128-aligned
template<int CO, bool POOL>
__global__ __launch_bounds__(256) void k_layerN_mfma(
    const bf16*  __restrict__ xin,   // [64][NT_COLS] raw conv+bias of prev layer
    const float* __restrict__ wN,    // [CO][64]
    const float* __restrict__ bN,    // [CO]
    const float* __restrict__ scsh,  // sc[64], sh[64] for input BN
    float*       __restrict__ accum, // [NBUCK][2*CO] bucketed stats
    bf16*        __restrict__ xout,  // [CO][NT_COLS]      (if !POOL)
    float*       __restrict__ mx) {  // [CO][NT_COLS/NK]   (if POOL)
  constexpr int RT = CO/16;
  __shared__ short xT[256*XT_STRIDE];       // BN'd input, transposed [col][c]
  __shared__ float sc_s[64], sh_s[64], bias_s[CO];
  const int t = threadIdx.x;
  const int col0 = blockIdx.x * 256;
  if (t < 64) { sc_s[t] = scsh[t]; sh_s[t] = scsh[64+t]; }
  if (t < CO) bias_s[t] = bN[t];
  __syncthreads();
  {
    const int col = col0 + t;
    #pragma unroll
    for (int c0 = 0; c0 < 64; c0 += 8) {
      short8 pk;
      #pragma unroll
      for (int j = 0; j < 8; ++j) {
        float v = __bfloat162float(xin[(size_t)(c0+j)*NT_COLS + col]);
        v = fmaxf(fmaf(v, sc_s[c0+j], sh_s[c0+j]), 0.f);
        pk[j] = (short)f2bf_bits(v);
      }
      *((short8*)&xT[t*XT_STRIDE + c0]) = pk;
    }
  }
  __syncthreads();
  const int lane = t & 63, wv = t >> 6;
  const int qd = lane >> 4, ln = lane & 15;
  short8 A[RT][2];
  #pragma unroll
  for (int rt = 0; rt < RT; ++rt) {
    #pragma unroll
    for (int kh = 0; kh < 2; ++kh) {
      const float* wp = wN + (size_t)(rt*16 + ln)*64 + kh*32 + qd*8;
      float4 f0 = *(const float4*)wp;
      float4 f1 = *(const float4*)(wp + 4);
      short8 a;
      a[0]=(short)f2bf_bits(f0.x); a[1]=(short)f2bf_bits(f0.y);
      a[2]=(short)f2bf_bits(f0.z); a[3]=(short)f2bf_bits(f0.w);
      a[4]=(short)f2bf_bits(f1.x); a[5]=(short)f2bf_bits(f1.y);
      a[6]=(short)f2bf_bits(f1.z); a[7]=(short)f2bf_bits(f1.w);
      A[rt][kh] = a;
    }
  }
  floatx4 acc[RT][4];
  #pragma unroll
  for (int rt = 0; rt < RT; ++rt)
    #pragma unroll
    for (int ct = 0; ct < 4; ++ct)
      acc[rt][ct] = (floatx4)0.f;
  #pragma unroll
  for (int ct = 0; ct < 4; ++ct) {
    const int coll = wv*64 + ct*16 + ln;
    short8 B0 = *((const short8*)&xT[coll*XT_STRIDE + qd*8]);
    short8 B1 = *((const short8*)&xT[coll*XT_STRIDE + 32 + qd*8]);
    #pragma unroll
    for (int rt = 0; rt < RT; ++rt) {
      acc[rt][ct] = __builtin_amdgcn_mfma_f32_16x16x32_bf16(A[rt][0], B0, acc[rt][ct], 0,0,0);
      acc[rt][ct] = __builtin_amdgcn_mfma_f32_16x16x32_bf16(A[rt][1], B1, acc[rt][ct], 0,0,0);
    }
  }
  float* dst = accum + (size_t)(blockIdx.x & (NBUCK-1))*(2*CO);
  const int bs0 = (col0 + wv*64) >> 5;     // wave covers bs0, bs0+1
  #pragma unroll
  for (int rt = 0; rt < RT; ++rt) {
    float s[4]  = {0.f,0.f,0.f,0.f};
    float sq[4] = {0.f,0.f,0.f,0.f};
    float mxv[2][4];
    #pragma unroll
    for (int h = 0; h < 2; ++h)
      #pragma unroll
      for (int r = 0; r < 4; ++r) mxv[h][r] = -3.402823466e38f;
    #pragma unroll
    for (int ct = 0; ct < 4; ++ct) {
      const int col = col0 + wv*64 + ct*16 + ln;
      #pragma unroll
      for (int r = 0; r < 4; ++r) {
        const int o = rt*16 + qd*4 + r;
        float v = acc[rt][ct][r] + bias_s[o];
        if (!POOL) xout[(size_t)o*NT_COLS + col] = __float2bfloat16(v);
        else mxv[ct>>1][r] = fmaxf(mxv[ct>>1][r], v);
        s[r] += v; sq[r] = fmaf(v, v, sq[r]);
      }
    }
    if (POOL) {
      #pragma unroll
      for (int h = 0; h < 2; ++h) {
        #pragma unroll
        for (int r = 0; r < 4; ++r) {
          float m = mxv[h][r];
          m = fmax_dpp<0x111,0xF,0xF>(m);
          m = fmax_dpp<0x112,0xF,0xF>(m);
          m = fmax_dpp<0x114,0xF,0xF>(m);
          m = fmax_dpp<0x118,0xF,0xF>(m);
          if (ln == 15) {
            const int o = rt*16 + qd*4 + r;
            mx[(size_t)o*(NT_COLS/NK) + bs0 + h] = m;
          }
        }
      }
    }
    #pragma unroll
    for (int r = 0; r < 4; ++r) {
      float a = s[r], q = sq[r];
      a = add_dpp<0x111>(a); a = add_dpp<0x112>(a);
      a = add_dpp<0x114>(a); a = add_dpp<0x118>(a);
      q = add_dpp<0x111>(q); q = add_dpp<0x112>(q);
      q = add_dpp<0x114>(q); q = add_dpp<0x118>(q);
      if (ln == 15) {
        const int o = rt*16 + qd*4 + r;
        atomicAdd(&dst[o], a);
        atomicAdd(&dst[CO + o], q);
      }
    }
  }
}

// ---------------- final BN+ReLU on pooled maxes (fp32 out) ------------------
__global__ __launch_bounds__(256) void k_bnmax(const float* __restrict__ mx,
                                               const float* __restrict__ scsh,
                                               float* __restrict__ out1) {
  const int blk = blockIdx.x;        // 16 b x 128 o
  const int o = blk & 127;
  const int b = blk >> 7;
  const float sc = scsh[o], sh = scsh[128+o];
  const int s = threadIdx.x * 4;
  float4 v = *(const float4*)(mx + (size_t)o*(NT_COLS/NK) + b*NS + s);
  float4 r;
  r.x = fmaxf(fmaf(v.x, sc, sh), 0.f);
  r.y = fmaxf(fmaf(v.y, sc, sh), 0.f);
  r.z = fmaxf(fmaf(v.z, sc, sh), 0.f);
  r.w = fmaxf(fmaf(v.w, sc, sh), 0.f);
  *(float4*)(out1 + (size_t)(b*128 + o)*NS + s) = r;
}

extern "C" void kernel_launch(void* const* d_in, const int* in_sizes, int n_in,
                              void* d_out, int out_size, void* d_ws, size_t ws_size,
                              hipStream_t stream) {
  const float* xyz  = (const float*)d_in[0];
  const float* feat = (const float*)d_in[1];
  const float* w0 = (const float*)d_in[2];
  const float* b0 = (const float*)d_in[3];
  const float* g0 = (const float*)d_in[4];
  const float* bt0= (const float*)d_in[5];
  const float* w1 = (const float*)d_in[6];
  const float* b1 = (const float*)d_in[7];
  const float* g1 = (const float*)d_in[8];
  const float* bt1= (const float*)d_in[9];
  const float* w2 = (const float*)d_in[10];
  const float* b2 = (const float*)d_in[11];
  const float* g2 = (const float*)d_in[12];
  const float* bt2= (const float*)d_in[13];

  float* out0 = (float*)d_out;                     // (B,3,NS) fp32
  float* out1 = out0 + (size_t)NB*3*NS;            // (B,128,NS) fp32

  // Workspace (max offset 145,033,216 B ~= 138 MB; ws >= 194 MB proven):
  //   accum@0 (128KB), scsh@131072, newxyz@133120, bidx@329728,
  //   x2@2426880 (64MB), x1@69535744 (64MB), mx3@136644608 (8MB fp32)
  char* ws = (char*)d_ws;
  float* accum  = (float*)(ws + 0);
  float* acc_l1 = accum;                 // NBUCK x 128
  float* acc_l2 = accum + 8192;          // NBUCK x 128
  float* acc_l3 = accum + 16384;         // NBUCK x 256
  float* scsh   = (float*)(ws + 131072);
  float* newxyz = (float*)(ws + 133120);
  int*   bidx   = (int*)  (ws + 329728);
  bf16*  x2     = (bf16*) (ws + 2426880);
  bf16*  x1     = (bf16*) (ws + 69535744);
  float* mx3    = (float*)(ws + 136644608);

  k_zero <<<128, 256, 0, stream>>>(accum);

  k_fps  <<<NB,   256, 0, stream>>>(xyz, newxyz, out0);
  k_ballq<<<16384/4, 256, 0, stream>>>(xyz, newxyz, bidx);
  k_layer1<<<NT_COLS/256, 256, 0, stream>>>(xyz, feat, newxyz, bidx, w0, b0, x1);

  k_stats   <<<64*32, 256, 0, stream>>>(x1, acc_l1, 64);
  k_finalize<<<1,     256, 0, stream>>>(acc_l1, g0, bt0, scsh + 0, 64);

  k_layerN_mfma<64,false><<<NT_COLS/256, 256, 0, stream>>>(x1, w1, b1, scsh + 0, acc_l2, x2, nullptr);
  k_finalize<<<1,     256, 0, stream>>>(acc_l2, g1, bt1, scsh + 128, 64);

  k_layerN_mfma<128,true><<<NT_COLS/256, 256, 0, stream>>>(x2, w2, b2, scsh + 128, acc_l3, nullptr, mx3);
  k_finalize<<<1,     256, 0, stream>>>(acc_l3, g2, bt2, scsh + 256, 128);

  k_bnmax <<<NB*128, 256, 0, stream>>>(mx3, scsh + 256, out1);
}

// Round 10
// 1085.501 us; speedup vs baseline: 1.0485x; 1.0485x over previous
//
#include <hip/hip_runtime.h>
#include <hip/hip_bf16.h>
#include <stdint.h>

#define NB 16
#define NPTS 4096
#define NS 1024
#define NK 32
#define NT_COLS (NB*NS*NK)   // 524288 columns (b*NS+s)*NK + k
#define NBUCK 64             // stat-accumulator buckets

typedef __hip_bfloat16 bf16;
typedef __attribute__((ext_vector_type(8))) short short8;   // 8 bf16 (4 VGPRs)
typedef __attribute__((ext_vector_type(4))) float floatx4;  // MFMA C/D
typedef __attribute__((ext_vector_type(2))) float floatx2;  // pk-fp32 pair

__device__ __forceinline__ unsigned short f2bf_bits(float v) {
  bf16 b = __float2bfloat16(v);
  return *(unsigned short*)&b;
}

// Packed fp32 ops (CDNA2+ VOP3P): per-half IEEE round-nearest, identical to
// __fadd_rn/__fmul_rn. Used to halve the FPS dist-loop issue count.
__device__ __forceinline__ floatx2 pk_add(floatx2 a, floatx2 b) {
  floatx2 d;
  asm("v_pk_add_f32 %0, %1, %2" : "=v"(d) : "v"(a), "v"(b));
  return d;
}
__device__ __forceinline__ floatx2 pk_mul(floatx2 a, floatx2 b) {
  floatx2 d;
  asm("v_pk_mul_f32 %0, %1, %2" : "=v"(d) : "v"(a), "v"(b));
  return d;
}

__global__ void k_zero(float* __restrict__ p) {
  p[blockIdx.x*256 + threadIdx.x] = 0.f;
}

// DPP-shifted fmax (verified gfx950 R5/R7/R8). Inactive/OOB src lanes keep old=x.
template<int CTRL, int RM, int BM>
__device__ __forceinline__ float fmax_dpp(float x) {
  int o = __builtin_amdgcn_update_dpp(__float_as_int(x), __float_as_int(x),
                                      CTRL, RM, BM, false);
  return fmaxf(x, __int_as_float(o));
}
// DPP-shifted add with zero-fill; 4-step chain sums 16-lane row onto lane 15.
template<int CTRL>
__device__ __forceinline__ float add_dpp(float x) {
  int o = __builtin_amdgcn_update_dpp(0, __float_as_int(x), CTRL, 0xF, 0xF, true);
  return __fadd_rn(x, __int_as_float(o));
}

// ---------------- FPS: R8 structure + pk-fp32 dist + coord-carry ------------
// np-exact: (x-c)^2 elementwise via x+(-c) (bit-identical to __fsub_rn) and
// sequential 3-term sum, no FMA. First-occurrence argmax at all levels:
// in-lane ascending strict >, in-wave lowest lane via ctz(ballot), cross-wave
// strict > in ascending wave order. Scalar xs/ys/zs LDS layout (R9's float4
// layout caused 16-way bank conflicts — reverted). Winner coords prefetched
// per-lane before the DPP chain and carried through the pair exchange, so no
// dependent xs[cur] fetch sits on the post-barrier serial path.
__global__ __launch_bounds__(256) void k_fps(const float* __restrict__ xyz,
                                             float* __restrict__ newxyz,
                                             float* __restrict__ out0) {
  __shared__ float xs[NPTS], ys[NPTS], zs[NPTS];
  __shared__ float selx[NS], sely[NS], selz[NS];
  __shared__ float4 pair[2][4];             // (M, x, y, z) per wave, dbuf
  const int b = blockIdx.x;
  const int t = threadIdx.x;
  const float* p = xyz + (size_t)b * 3 * NPTS;
  for (int i = t; i < NPTS; i += 256) {
    xs[i] = p[i];
    ys[i] = p[NPTS + i];
    zs[i] = p[2*NPTS + i];
  }
  __syncthreads();
  floatx2 px[8], py[8], pz[8];
  float dist[16];
  const int p0 = t * 16;
  #pragma unroll
  for (int j2 = 0; j2 < 8; ++j2) {
    px[j2] = (floatx2){xs[p0+2*j2], xs[p0+2*j2+1]};
    py[j2] = (floatx2){ys[p0+2*j2], ys[p0+2*j2+1]};
    pz[j2] = (floatx2){zs[p0+2*j2], zs[p0+2*j2+1]};
    dist[2*j2] = 1e10f; dist[2*j2+1] = 1e10f;
  }
  const int lane = t & 63, wv = t >> 6;
  float cx = xs[0], cy = ys[0], cz = zs[0];
  for (int i = 0; i < NS; ++i) {
    if (t == 0) { selx[i] = cx; sely[i] = cy; selz[i] = cz; }
    if (i == NS-1) break;
    const float nxs = -cx, nys = -cy, nzs = -cz;      // exact sign flips
    const floatx2 ncx = (floatx2){nxs, nxs};
    const floatx2 ncy = (floatx2){nys, nys};
    const floatx2 ncz = (floatx2){nzs, nzs};
    float bv = -1.0f; int bi = p0;
    #pragma unroll
    for (int j2 = 0; j2 < 8; ++j2) {
      floatx2 dx = pk_add(px[j2], ncx);               // == __fsub_rn(px, cx)
      floatx2 dy = pk_add(py[j2], ncy);
      floatx2 dz = pk_add(pz[j2], ncz);
      floatx2 d  = pk_add(pk_add(pk_mul(dx,dx), pk_mul(dy,dy)), pk_mul(dz,dz));
      float nd0 = fminf(dist[2*j2],   d.x);
      float nd1 = fminf(dist[2*j2+1], d.y);
      dist[2*j2] = nd0; dist[2*j2+1] = nd1;
      if (nd0 > bv) { bv = nd0; bi = p0 + 2*j2; }     // strict > => first occ.
      if (nd1 > bv) { bv = nd1; bi = p0 + 2*j2 + 1; }
    }
    // prefetch candidate coords; latency hides under DPP chain + ballot
    float candx = xs[bi], candy = ys[bi], candz = zs[bi];
    // wave64 max via DPP chain (converges to lane 63)
    float x = bv;
    x = fmax_dpp<0x111,0xF,0xF>(x);   // row_shr:1
    x = fmax_dpp<0x112,0xF,0xF>(x);   // row_shr:2
    x = fmax_dpp<0x114,0xF,0xF>(x);   // row_shr:4
    x = fmax_dpp<0x118,0xF,0xF>(x);   // row_shr:8
    x = fmax_dpp<0x142,0xA,0xF>(x);   // row_bcast:15 -> rows 1,3
    x = fmax_dpp<0x143,0xC,0xF>(x);   // row_bcast:31 -> rows 2,3
    float M = __int_as_float(__builtin_amdgcn_readlane(__float_as_int(x), 63));
    unsigned long long mk = __ballot(bv == M);
    int sl = (int)__builtin_ctzll(mk);                // lowest lane = smallest idx
    if (lane == sl) pair[i & 1][wv] = make_float4(M, candx, candy, candz);
    __syncthreads();
    float4 q0 = pair[i & 1][0];
    float4 q1 = pair[i & 1][1];
    float4 q2 = pair[i & 1][2];
    float4 q3 = pair[i & 1][3];
    float bestv = q0.x; float wx = q0.y, wy = q0.z, wz = q0.w;
    if (q1.x > bestv) { bestv = q1.x; wx = q1.y; wy = q1.z; wz = q1.w; }
    if (q2.x > bestv) { bestv = q2.x; wx = q2.y; wy = q2.z; wz = q2.w; }
    if (q3.x > bestv) { bestv = q3.x; wx = q3.y; wy = q3.z; wz = q3.w; }
    cx = wx; cy = wy; cz = wz;                        // uniform across block
  }
  __syncthreads();
  for (int i = t; i < NS; i += 256) {
    float vx = selx[i], vy = sely[i], vz = selz[i];
    size_t q = (size_t)b*3*NS + i;
    out0[q] = vx; out0[q + NS] = vy; out0[q + 2*NS] = vz;   // bit-exact copies
    size_t o = (size_t)(b*NS + i)*3;
    newxyz[o] = vx; newxyz[o+1] = vy; newxyz[o+2] = vz;
  }
}

// ---------------- Ball query: one wave per query ----------------------------
__global__ __launch_bounds__(256) void k_ballq(const float* __restrict__ xyz,
                                               const float* __restrict__ newxyz,
                                               int* __restrict__ idx) {
  const int gw = (blockIdx.x * 256 + threadIdx.x) >> 6;
  const int lane = threadIdx.x & 63;
  const int b = gw >> 10;
  const int s = gw & (NS-1);
  const float* xb = xyz + (size_t)b * 3 * NPTS;
  const size_t nq = (size_t)(b*NS + s)*3;
  const float nx = newxyz[nq], ny = newxyz[nq+1], nz = newxyz[nq+2];
  const float sn = __fadd_rn(__fadd_rn(__fmul_rn(nx,nx), __fmul_rn(ny,ny)), __fmul_rn(nz,nz));
  const float R2 = (float)(0.2*0.2);
  int* out = idx + (size_t)gw * NK;
  int cnt = 0, first = 0;
  for (int c0 = 0; c0 < NPTS; c0 += 64) {
    int n = c0 + lane;
    float x = xb[n], y = xb[NPTS+n], z = xb[2*NPTS+n];
    float sx = __fadd_rn(__fadd_rn(__fmul_rn(x,x), __fmul_rn(y,y)), __fmul_rn(z,z));
    float dt = __fadd_rn(__fadd_rn(__fmul_rn(nx,x), __fmul_rn(ny,y)), __fmul_rn(nz,z));
    float sqr = __fsub_rn(__fadd_rn(sn, sx), __fmul_rn(2.0f, dt));
    bool inr = (sqr <= R2);
    unsigned long long m = __ballot(inr);
    if (m != 0ull) {
      if (cnt == 0) first = c0 + (int)__builtin_ctzll(m);
      int rank = __popcll(m & ((1ull << lane) - 1ull));
      int pos = cnt + rank;
      if (inr && pos < NK) out[pos] = n;
      cnt += __popcll(m);
      if (cnt >= NK) break;
    }
  }
  int tot = cnt < NK ? cnt : NK;
  if (lane >= tot && lane < NK) out[lane] = first;
}

// ---------------- Layer 1: gather + 6->64 conv -----------------------------
__global__ __launch_bounds__(256) void k_layer1(const float* __restrict__ xyz,
                                                const float* __restrict__ feat,
                                                const float* __restrict__ newxyz,
                                                const int* __restrict__ idx,
                                                const float* __restrict__ w0,
                                                const float* __restrict__ b0,
                                                bf16* __restrict__ x1) {
  __shared__ float w[64*6];
  __shared__ float bias[64];
  for (int i = threadIdx.x; i < 64*6; i += 256) w[i] = w0[i];
  if (threadIdx.x < 64) bias[threadIdx.x] = b0[threadIdx.x];
  __syncthreads();
  const int col = blockIdx.x * 256 + threadIdx.x;
  const int bs = col >> 5;
  const int b  = bs >> 10;
  const int n  = idx[col];
  const float* xb = xyz  + (size_t)b*3*NPTS;
  const float* fb = feat + (size_t)b*3*NPTS;
  float in[6];
  in[0] = __fsub_rn(xb[n],        newxyz[(size_t)bs*3]);
  in[1] = __fsub_rn(xb[NPTS+n],   newxyz[(size_t)bs*3+1]);
  in[2] = __fsub_rn(xb[2*NPTS+n], newxyz[(size_t)bs*3+2]);
  in[3] = fb[n];
  in[4] = fb[NPTS+n];
  in[5] = fb[2*NPTS+n];
  #pragma unroll
  for (int o = 0; o < 64; ++o) {
    float acc = bias[o];
    #pragma unroll
    for (int c = 0; c < 6; ++c) acc = fmaf(in[c], w[o*6+c], acc);
    x1[(size_t)o*NT_COLS + col] = __float2bfloat16(acc);
  }
}

// ---------------- Per-channel sum/sumsq for x1 (bucketed accum) -------------
__global__ __launch_bounds__(256) void k_stats(const bf16* __restrict__ x,
                                               float* __restrict__ accum, int C) {
  const int o = blockIdx.x >> 5;
  const int chunk = blockIdx.x & 31;
  const uint4* p = (const uint4*)(x + (size_t)o*NT_COLS + (size_t)chunk*16384);
  float s = 0.f, ss = 0.f;
  #pragma unroll
  for (int it = 0; it < 8; ++it) {
    uint4 u = p[threadIdx.x + it*256];
    uint32_t wr[4] = {u.x, u.y, u.z, u.w};
    #pragma unroll
    for (int q = 0; q < 4; ++q) {
      float a  = __uint_as_float(wr[q] << 16);
      float bq = __uint_as_float(wr[q] & 0xffff0000u);
      s += a;  ss = fmaf(a, a, ss);
      s += bq; ss = fmaf(bq, bq, ss);
    }
  }
  #pragma unroll
  for (int off = 32; off; off >>= 1) { s += __shfl_xor(s, off); ss += __shfl_xor(ss, off); }
  __shared__ float ls[4], lss[4];
  const int lane = threadIdx.x & 63, wv = threadIdx.x >> 6;
  if (lane == 0) { ls[wv] = s; lss[wv] = ss; }
  __syncthreads();
  if (threadIdx.x == 0) {
    float* dst = accum + (size_t)(blockIdx.x & (NBUCK-1))*(2*C);
    atomicAdd(&dst[o],     (ls[0]+ls[1])+(ls[2]+ls[3]));
    atomicAdd(&dst[C + o], (lss[0]+lss[1])+(lss[2]+lss[3]));
  }
}

// ---------------- finalize: sum buckets -> sc/sh ---------------------------
__global__ void k_finalize(const float* __restrict__ accum,
                           const float* __restrict__ g, const float* __restrict__ beta,
                           float* __restrict__ scsh, int C) {
  int o = threadIdx.x;
  if (o < C) {
    float s = 0.f, ss = 0.f;
    for (int bkt = 0; bkt < NBUCK; ++bkt) {
      s  += accum[(size_t)bkt*(2*C) + o];
      ss += accum[(size_t)bkt*(2*C) + C + o];
    }
    const float n = (float)NT_COLS;
    float mu  = s / n;
    float var = ss / n - mu*mu;
    if (var < 0.f) var = 0.f;
    float rs = rsqrtf(var + 1e-5f);
    float sc = g[o] * rs;
    scsh[o]   = sc;
    scsh[C+o] = beta[o] - mu * sc;
  }
}

// ---------------- Layers 2/3: MFMA GEMM + fused stats (+ fused max) --------
#define XT_STRIDE 72   // bf16 elems; 144 B row -> b128-aligned
template<int CO, bool POOL>
__global__ __launch_bounds__(256) void k_layerN_mfma(
    const bf16*  __restrict__ xin,   // [64][NT_COLS] raw conv+bias of prev layer
    const float* __restrict__ wN,    // [CO][64]
    const float* __restrict__ bN,    // [CO]
    const float* __restrict__ scsh,  // sc[64], sh[64] for input BN
    float*       __restrict__ accum, // [NBUCK][2*CO] bucketed stats
    bf16*        __restrict__ xout,  // [CO][NT_COLS]      (if !POOL)
    float*       __restrict__ mx) {  // [CO][NT_COLS/NK]   (if POOL)
  constexpr int RT = CO/16;
  __shared__ short xT[256*XT_STRIDE];       // BN'd input, transposed [col][c]
  __shared__ float sc_s[64], sh_s[64], bias_s[CO];
  const int t = threadIdx.x;
  const int col0 = blockIdx.x * 256;
  if (t < 64) { sc_s[t] = scsh[t]; sh_s[t] = scsh[64+t]; }
  if (t < CO) bias_s[t] = bN[t];
  __syncthreads();
  {
    const int col = col0 + t;
    #pragma unroll
    for (int c0 = 0; c0 < 64; c0 += 8) {
      short8 pk;
      #pragma unroll
      for (int j = 0; j < 8; ++j) {
        float v = __bfloat162float(xin[(size_t)(c0+j)*NT_COLS + col]);
        v = fmaxf(fmaf(v, sc_s[c0+j], sh_s[c0+j]), 0.f);
        pk[j] = (short)f2bf_bits(v);
      }
      *((short8*)&xT[t*XT_STRIDE + c0]) = pk;
    }
  }
  __syncthreads();
  const int lane = t & 63, wv = t >> 6;
  const int qd = lane >> 4, ln = lane & 15;
  short8 A[RT][2];
  #pragma unroll
  for (int rt = 0; rt < RT; ++rt) {
    #pragma unroll
    for (int kh = 0; kh < 2; ++kh) {
      const float* wp = wN + (size_t)(rt*16 + ln)*64 + kh*32 + qd*8;
      float4 f0 = *(const float4*)wp;
      float4 f1 = *(const float4*)(wp + 4);
      short8 a;
      a[0]=(short)f2bf_bits(f0.x); a[1]=(short)f2bf_bits(f0.y);
      a[2]=(short)f2bf_bits(f0.z); a[3]=(short)f2bf_bits(f0.w);
      a[4]=(short)f2bf_bits(f1.x); a[5]=(short)f2bf_bits(f1.y);
      a[6]=(short)f2bf_bits(f1.z); a[7]=(short)f2bf_bits(f1.w);
      A[rt][kh] = a;
    }
  }
  floatx4 acc[RT][4];
  #pragma unroll
  for (int rt = 0; rt < RT; ++rt)
    #pragma unroll
    for (int ct = 0; ct < 4; ++ct)
      acc[rt][ct] = (floatx4)0.f;
  #pragma unroll
  for (int ct = 0; ct < 4; ++ct) {
    const int coll = wv*64 + ct*16 + ln;
    short8 B0 = *((const short8*)&xT[coll*XT_STRIDE + qd*8]);
    short8 B1 = *((const short8*)&xT[coll*XT_STRIDE + 32 + qd*8]);
    #pragma unroll
    for (int rt = 0; rt < RT; ++rt) {
      acc[rt][ct] = __builtin_amdgcn_mfma_f32_16x16x32_bf16(A[rt][0], B0, acc[rt][ct], 0,0,0);
      acc[rt][ct] = __builtin_amdgcn_mfma_f32_16x16x32_bf16(A[rt][1], B1, acc[rt][ct], 0,0,0);
    }
  }
  float* dst = accum + (size_t)(blockIdx.x & (NBUCK-1))*(2*CO);
  const int bs0 = (col0 + wv*64) >> 5;     // wave covers bs0, bs0+1
  #pragma unroll
  for (int rt = 0; rt < RT; ++rt) {
    float s[4]  = {0.f,0.f,0.f,0.f};
    float sq[4] = {0.f,0.f,0.f,0.f};
    float mxv[2][4];
    #pragma unroll
    for (int h = 0; h < 2; ++h)
      #pragma unroll
      for (int r = 0; r < 4; ++r) mxv[h][r] = -3.402823466e38f;
    #pragma unroll
    for (int ct = 0; ct < 4; ++ct) {
      const int col = col0 + wv*64 + ct*16 + ln;
      #pragma unroll
      for (int r = 0; r < 4; ++r) {
        const int o = rt*16 + qd*4 + r;
        float v = acc[rt][ct][r] + bias_s[o];
        if (!POOL) xout[(size_t)o*NT_COLS + col] = __float2bfloat16(v);
        else mxv[ct>>1][r] = fmaxf(mxv[ct>>1][r], v);
        s[r] += v; sq[r] = fmaf(v, v, sq[r]);
      }
    }
    if (POOL) {
      #pragma unroll
      for (int h = 0; h < 2; ++h) {
        #pragma unroll
        for (int r = 0; r < 4; ++r) {
          float m = mxv[h][r];
          m = fmax_dpp<0x111,0xF,0xF>(m);
          m = fmax_dpp<0x112,0xF,0xF>(m);
          m = fmax_dpp<0x114,0xF,0xF>(m);
          m = fmax_dpp<0x118,0xF,0xF>(m);
          if (ln == 15) {
            const int o = rt*16 + qd*4 + r;
            mx[(size_t)o*(NT_COLS/NK) + bs0 + h] = m;
          }
        }
      }
    }
    #pragma unroll
    for (int r = 0; r < 4; ++r) {
      float a = s[r], q = sq[r];
      a = add_dpp<0x111>(a); a = add_dpp<0x112>(a);
      a = add_dpp<0x114>(a); a = add_dpp<0x118>(a);
      q = add_dpp<0x111>(q); q = add_dpp<0x112>(q);
      q = add_dpp<0x114>(q); q = add_dpp<0x118>(q);
      if (ln == 15) {
        const int o = rt*16 + qd*4 + r;
        atomicAdd(&dst[o], a);
        atomicAdd(&dst[CO + o], q);
      }
    }
  }
}

// ---------------- final BN+ReLU on pooled maxes (fp32 out) ------------------
__global__ __launch_bounds__(256) void k_bnmax(const float* __restrict__ mx,
                                               const float* __restrict__ scsh,
                                               float* __restrict__ out1) {
  const int blk = blockIdx.x;        // 16 b x 128 o
  const int o = blk & 127;
  const int b = blk >> 7;
  const float sc = scsh[o], sh = scsh[128+o];
  const int s = threadIdx.x * 4;
  float4 v = *(const float4*)(mx + (size_t)o*(NT_COLS/NK) + b*NS + s);
  float4 r;
  r.x = fmaxf(fmaf(v.x, sc, sh), 0.f);
  r.y = fmaxf(fmaf(v.y, sc, sh), 0.f);
  r.z = fmaxf(fmaf(v.z, sc, sh), 0.f);
  r.w = fmaxf(fmaf(v.w, sc, sh), 0.f);
  *(float4*)(out1 + (size_t)(b*128 + o)*NS + s) = r;
}

extern "C" void kernel_launch(void* const* d_in, const int* in_sizes, int n_in,
                              void* d_out, int out_size, void* d_ws, size_t ws_size,
                              hipStream_t stream) {
  const float* xyz  = (const float*)d_in[0];
  const float* feat = (const float*)d_in[1];
  const float* w0 = (const float*)d_in[2];
  const float* b0 = (const float*)d_in[3];
  const float* g0 = (const float*)d_in[4];
  const float* bt0= (const float*)d_in[5];
  const float* w1 = (const float*)d_in[6];
  const float* b1 = (const float*)d_in[7];
  const float* g1 = (const float*)d_in[8];
  const float* bt1= (const float*)d_in[9];
  const float* w2 = (const float*)d_in[10];
  const float* b2 = (const float*)d_in[11];
  const float* g2 = (const float*)d_in[12];
  const float* bt2= (const float*)d_in[13];

  float* out0 = (float*)d_out;                     // (B,3,NS) fp32
  float* out1 = out0 + (size_t)NB*3*NS;            // (B,128,NS) fp32

  // Workspace (max offset 145,033,216 B ~= 138 MB; ws >= 194 MB proven):
  //   accum@0 (128KB), scsh@131072, newxyz@133120, bidx@329728,
  //   x2@2426880 (64MB), x1@69535744 (64MB), mx3@136644608 (8MB fp32)
  char* ws = (char*)d_ws;
  float* accum  = (float*)(ws + 0);
  float* acc_l1 = accum;                 // NBUCK x 128
  float* acc_l2 = accum + 8192;          // NBUCK x 128
  float* acc_l3 = accum + 16384;         // NBUCK x 256
  float* scsh   = (float*)(ws + 131072);
  float* newxyz = (float*)(ws + 133120);
  int*   bidx   = (int*)  (ws + 329728);
  bf16*  x2     = (bf16*) (ws + 2426880);
  bf16*  x1     = (bf16*) (ws + 69535744);
  float* mx3    = (float*)(ws + 136644608);

  k_zero <<<128, 256, 0, stream>>>(accum);

  k_fps  <<<NB,   256, 0, stream>>>(xyz, newxyz, out0);
  k_ballq<<<16384/4, 256, 0, stream>>>(xyz, newxyz, bidx);
  k_layer1<<<NT_COLS/256, 256, 0, stream>>>(xyz, feat, newxyz, bidx, w0, b0, x1);

  k_stats   <<<64*32, 256, 0, stream>>>(x1, acc_l1, 64);
  k_finalize<<<1,     256, 0, stream>>>(acc_l1, g0, bt0, scsh + 0, 64);

  k_layerN_mfma<64,false><<<NT_COLS/256, 256, 0, stream>>>(x1, w1, b1, scsh + 0, acc_l2, x2, nullptr);
  k_finalize<<<1,     256, 0, stream>>>(acc_l2, g1, bt1, scsh + 128, 64);

  k_layerN_mfma<128,true><<<NT_COLS/256, 256, 0, stream>>>(x2, w2, b2, scsh + 128, acc_l3, nullptr, mx3);
  k_finalize<<<1,     256, 0, stream>>>(acc_l3, g2, bt2, scsh + 256, 128);

  k_bnmax <<<NB*128, 256, 0, stream>>>(mx3, scsh + 256, out1);
}

// Round 11
// 1073.365 us; speedup vs baseline: 1.0604x; 1.0113x over previous
//
#include <hip/hip_runtime.h>
#include <hip/hip_bf16.h>
#include <stdint.h>

#define NB 16
#define NPTS 4096
#define NS 1024
#define NK 32
#define NT_COLS (NB*NS*NK)   // 524288 columns (b*NS+s)*NK + k
#define NBUCK 64             // stat-accumulator buckets

typedef __hip_bfloat16 bf16;
typedef __attribute__((ext_vector_type(8))) short short8;   // 8 bf16 (4 VGPRs)
typedef __attribute__((ext_vector_type(4))) float floatx4;  // MFMA C/D

__device__ __forceinline__ unsigned short f2bf_bits(float v) {
  bf16 b = __float2bfloat16(v);
  return *(unsigned short*)&b;
}

__global__ void k_zero(float* __restrict__ p) {
  p[blockIdx.x*256 + threadIdx.x] = 0.f;
}

// DPP-shifted fmax (verified gfx950 R5/R7/R8). Inactive/OOB src lanes keep old=x.
template<int CTRL, int RM, int BM>
__device__ __forceinline__ float fmax_dpp(float x) {
  int o = __builtin_amdgcn_update_dpp(__float_as_int(x), __float_as_int(x),
                                      CTRL, RM, BM, false);
  return fmaxf(x, __int_as_float(o));
}
// DPP add with zero-fill identity; RM-masked rows add 0 (old=0).
template<int CTRL, int RM>
__device__ __forceinline__ float add_dpp(float x) {
  int o = __builtin_amdgcn_update_dpp(0, __float_as_int(x), CTRL, RM, 0xF, true);
  return __fadd_rn(x, __int_as_float(o));
}
// 16-lane row sum -> lane 15 of each row (mfma C-layout stats).
__device__ __forceinline__ float add16_dpp(float x) {
  x = add_dpp<0x111,0xF>(x); x = add_dpp<0x112,0xF>(x);
  x = add_dpp<0x114,0xF>(x); x = add_dpp<0x118,0xF>(x);
  return x;
}
// full wave64 sum -> lane 63 (mirrors the proven fmax 6-step chain).
__device__ __forceinline__ float add64_dpp(float x) {
  x = add_dpp<0x111,0xF>(x); x = add_dpp<0x112,0xF>(x);
  x = add_dpp<0x114,0xF>(x); x = add_dpp<0x118,0xF>(x);
  x = add_dpp<0x142,0xA>(x);   // row_bcast:15 -> rows 1,3
  x = add_dpp<0x143,0xC>(x);   // row_bcast:31 -> rows 2,3
  return x;
}

// ---------------- FPS: R8 dist loop (579us, 3x measured) + coord-carry ------
// np-exact: (x-c)^2 elementwise, sequential 3-term sum, no FMA. First-occur
// argmax at all levels: in-lane ascending strict >, in-wave lowest lane via
// ctz(ballot), cross-wave strict > in ascending wave order. ONLY delta vs R8:
// winner coords prefetched per-lane before the DPP chain (latency hidden) and
// carried through the pair exchange, removing the dependent xs[cur] broadcast
// fetch from the post-barrier serial path.
__global__ __launch_bounds__(256) void k_fps(const float* __restrict__ xyz,
                                             float* __restrict__ newxyz,
                                             float* __restrict__ out0) {
  __shared__ float xs[NPTS], ys[NPTS], zs[NPTS];
  __shared__ float selx[NS], sely[NS], selz[NS];
  __shared__ float4 pair[2][4];             // (M, x, y, z) per wave, dbuf
  const int b = blockIdx.x;
  const int t = threadIdx.x;
  const float* p = xyz + (size_t)b * 3 * NPTS;
  for (int i = t; i < NPTS; i += 256) {
    xs[i] = p[i];
    ys[i] = p[NPTS + i];
    zs[i] = p[2*NPTS + i];
  }
  __syncthreads();
  float px[16], py[16], pz[16], dist[16];
  const int p0 = t * 16;
  #pragma unroll
  for (int j = 0; j < 16; ++j) {
    px[j]=xs[p0+j]; py[j]=ys[p0+j]; pz[j]=zs[p0+j]; dist[j]=1e10f;
  }
  const int lane = t & 63, wv = t >> 6;
  float cx = xs[0], cy = ys[0], cz = zs[0];
  for (int i = 0; i < NS; ++i) {
    if (t == 0) { selx[i] = cx; sely[i] = cy; selz[i] = cz; }
    if (i == NS-1) break;
    float bv = -1.0f; int bi = p0;
    #pragma unroll
    for (int j = 0; j < 16; ++j) {
      float dx = __fsub_rn(px[j], cx);
      float dy = __fsub_rn(py[j], cy);
      float dz = __fsub_rn(pz[j], cz);
      float d  = __fadd_rn(__fadd_rn(__fmul_rn(dx,dx), __fmul_rn(dy,dy)), __fmul_rn(dz,dz));
      float nd = fminf(dist[j], d);
      dist[j] = nd;
      if (nd > bv) { bv = nd; bi = p0 + j; }   // strict > => first occurrence
    }
    // prefetch candidate coords; latency hides under DPP chain + ballot
    float candx = xs[bi], candy = ys[bi], candz = zs[bi];
    // wave64 max via DPP chain (converges to lane 63)
    float x = bv;
    x = fmax_dpp<0x111,0xF,0xF>(x);   // row_shr:1
    x = fmax_dpp<0x112,0xF,0xF>(x);   // row_shr:2
    x = fmax_dpp<0x114,0xF,0xF>(x);   // row_shr:4
    x = fmax_dpp<0x118,0xF,0xF>(x);   // row_shr:8
    x = fmax_dpp<0x142,0xA,0xF>(x);   // row_bcast:15 -> rows 1,3
    x = fmax_dpp<0x143,0xC,0xF>(x);   // row_bcast:31 -> rows 2,3
    float M = __int_as_float(__builtin_amdgcn_readlane(__float_as_int(x), 63));
    unsigned long long mk = __ballot(bv == M);
    int sl = (int)__builtin_ctzll(mk);              // lowest lane = smallest idx
    if (lane == sl) pair[i & 1][wv] = make_float4(M, candx, candy, candz);
    __syncthreads();
    float4 q0 = pair[i & 1][0];
    float4 q1 = pair[i & 1][1];
    float4 q2 = pair[i & 1][2];
    float4 q3 = pair[i & 1][3];
    float bestv = q0.x; float wx = q0.y, wy = q0.z, wz = q0.w;
    if (q1.x > bestv) { bestv = q1.x; wx = q1.y; wy = q1.z; wz = q1.w; }
    if (q2.x > bestv) { bestv = q2.x; wx = q2.y; wy = q2.z; wz = q2.w; }
    if (q3.x > bestv) { bestv = q3.x; wx = q3.y; wy = q3.z; wz = q3.w; }
    cx = wx; cy = wy; cz = wz;                      // uniform across block
  }
  __syncthreads();
  for (int i = t; i < NS; i += 256) {
    float vx = selx[i], vy = sely[i], vz = selz[i];
    size_t q = (size_t)b*3*NS + i;
    out0[q] = vx; out0[q + NS] = vy; out0[q + 2*NS] = vz;   // bit-exact copies
    size_t o = (size_t)(b*NS + i)*3;
    newxyz[o] = vx; newxyz[o+1] = vy; newxyz[o+2] = vz;
  }
}

// ---------------- Ball query: one wave per query ----------------------------
__global__ __launch_bounds__(256) void k_ballq(const float* __restrict__ xyz,
                                               const float* __restrict__ newxyz,
                                               int* __restrict__ idx) {
  const int gw = (blockIdx.x * 256 + threadIdx.x) >> 6;
  const int lane = threadIdx.x & 63;
  const int b = gw >> 10;
  const int s = gw & (NS-1);
  const float* xb = xyz + (size_t)b * 3 * NPTS;
  const size_t nq = (size_t)(b*NS + s)*3;
  const float nx = newxyz[nq], ny = newxyz[nq+1], nz = newxyz[nq+2];
  const float sn = __fadd_rn(__fadd_rn(__fmul_rn(nx,nx), __fmul_rn(ny,ny)), __fmul_rn(nz,nz));
  const float R2 = (float)(0.2*0.2);
  int* out = idx + (size_t)gw * NK;
  int cnt = 0, first = 0;
  for (int c0 = 0; c0 < NPTS; c0 += 64) {
    int n = c0 + lane;
    float x = xb[n], y = xb[NPTS+n], z = xb[2*NPTS+n];
    float sx = __fadd_rn(__fadd_rn(__fmul_rn(x,x), __fmul_rn(y,y)), __fmul_rn(z,z));
    float dt = __fadd_rn(__fadd_rn(__fmul_rn(nx,x), __fmul_rn(ny,y)), __fmul_rn(nz,z));
    float sqr = __fsub_rn(__fadd_rn(sn, sx), __fmul_rn(2.0f, dt));
    bool inr = (sqr <= R2);
    unsigned long long m = __ballot(inr);
    if (m != 0ull) {
      if (cnt == 0) first = c0 + (int)__builtin_ctzll(m);
      int rank = __popcll(m & ((1ull << lane) - 1ull));
      int pos = cnt + rank;
      if (inr && pos < NK) out[pos] = n;
      cnt += __popcll(m);
      if (cnt >= NK) break;
    }
  }
  int tot = cnt < NK ? cnt : NK;
  if (lane >= tot && lane < NK) out[lane] = first;
}

// ---------------- Layer 1: gather + 6->64 conv + FUSED stats ----------------
__global__ __launch_bounds__(256) void k_layer1(const float* __restrict__ xyz,
                                                const float* __restrict__ feat,
                                                const float* __restrict__ newxyz,
                                                const int* __restrict__ idx,
                                                const float* __restrict__ w0,
                                                const float* __restrict__ b0,
                                                float* __restrict__ accum,
                                                bf16* __restrict__ x1) {
  __shared__ float w[64*6];
  __shared__ float bias[64];
  for (int i = threadIdx.x; i < 64*6; i += 256) w[i] = w0[i];
  if (threadIdx.x < 64) bias[threadIdx.x] = b0[threadIdx.x];
  __syncthreads();
  const int col = blockIdx.x * 256 + threadIdx.x;
  const int bs = col >> 5;
  const int b  = bs >> 10;
  const int n  = idx[col];
  const float* xb = xyz  + (size_t)b*3*NPTS;
  const float* fb = feat + (size_t)b*3*NPTS;
  float in[6];
  in[0] = __fsub_rn(xb[n],        newxyz[(size_t)bs*3]);
  in[1] = __fsub_rn(xb[NPTS+n],   newxyz[(size_t)bs*3+1]);
  in[2] = __fsub_rn(xb[2*NPTS+n], newxyz[(size_t)bs*3+2]);
  in[3] = fb[n];
  in[4] = fb[NPTS+n];
  in[5] = fb[2*NPTS+n];
  const int lane = threadIdx.x & 63;
  float* dst = accum + (size_t)(blockIdx.x & (NBUCK-1))*128;
  #pragma unroll
  for (int o = 0; o < 64; ++o) {
    float acc = bias[o];
    #pragma unroll
    for (int c = 0; c < 6; ++c) acc = fmaf(in[c], w[o*6+c], acc);
    x1[(size_t)o*NT_COLS + col] = __float2bfloat16(acc);
    // fused per-channel stats: wave64 sum -> lane 63 -> bucketed atomic
    float s = add64_dpp(acc);
    float q = add64_dpp(__fmul_rn(acc, acc));
    if (lane == 63) {
      atomicAdd(&dst[o], s);
      atomicAdd(&dst[64 + o], q);
    }
  }
}

// ---------------- finalize: sum buckets -> sc/sh ---------------------------
__global__ void k_finalize(const float* __restrict__ accum,
                           const float* __restrict__ g, const float* __restrict__ beta,
                           float* __restrict__ scsh, int C) {
  int o = threadIdx.x;
  if (o < C) {
    float s = 0.f, ss = 0.f;
    for (int bkt = 0; bkt < NBUCK; ++bkt) {
      s  += accum[(size_t)bkt*(2*C) + o];
      ss += accum[(size_t)bkt*(2*C) + C + o];
    }
    const float n = (float)NT_COLS;
    float mu  = s / n;
    float var = ss / n - mu*mu;
    if (var < 0.f) var = 0.f;
    float rs = rsqrtf(var + 1e-5f);
    float sc = g[o] * rs;
    scsh[o]   = sc;
    scsh[C+o] = beta[o] - mu * sc;
  }
}

// ---------------- Layers 2/3: MFMA GEMM + fused stats (+ fused max) --------
#define XT_STRIDE 72   // bf16 elems; 144 B row -> b128-aligned
template<int CO, bool POOL>
__global__ __launch_bounds__(256) void k_layerN_mfma(
    const bf16*  __restrict__ xin,   // [64][NT_COLS] raw conv+bias of prev layer
    const float* __restrict__ wN,    // [CO][64]
    const float* __restrict__ bN,    // [CO]
    const float* __restrict__ scsh,  // sc[64], sh[64] for input BN
    float*       __restrict__ accum, // [NBUCK][2*CO] bucketed stats
    bf16*        __restrict__ xout,  // [CO][NT_COLS]      (if !POOL)
    float*       __restrict__ mx) {  // [CO][NT_COLS/NK]   (if POOL)
  constexpr int RT = CO/16;
  __shared__ short xT[256*XT_STRIDE];       // BN'd input, transposed [col][c]
  __shared__ float sc_s[64], sh_s[64], bias_s[CO];
  const int t = threadIdx.x;
  const int col0 = blockIdx.x * 256;
  if (t < 64) { sc_s[t] = scsh[t]; sh_s[t] = scsh[64+t]; }
  if (t < CO) bias_s[t] = bN[t];
  __syncthreads();
  {
    const int col = col0 + t;
    #pragma unroll
    for (int c0 = 0; c0 < 64; c0 += 8) {
      short8 pk;
      #pragma unroll
      for (int j = 0; j < 8; ++j) {
        float v = __bfloat162float(xin[(size_t)(c0+j)*NT_COLS + col]);
        v = fmaxf(fmaf(v, sc_s[c0+j], sh_s[c0+j]), 0.f);
        pk[j] = (short)f2bf_bits(v);
      }
      *((short8*)&xT[t*XT_STRIDE + c0]) = pk;
    }
  }
  __syncthreads();
  const int lane = t & 63, wv = t >> 6;
  const int qd = lane >> 4, ln = lane & 15;
  short8 A[RT][2];
  #pragma unroll
  for (int rt = 0; rt < RT; ++rt) {
    #pragma unroll
    for (int kh = 0; kh < 2; ++kh) {
      const float* wp = wN + (size_t)(rt*16 + ln)*64 + kh*32 + qd*8;
      float4 f0 = *(const float4*)wp;
      float4 f1 = *(const float4*)(wp + 4);
      short8 a;
      a[0]=(short)f2bf_bits(f0.x); a[1]=(short)f2bf_bits(f0.y);
      a[2]=(short)f2bf_bits(f0.z); a[3]=(short)f2bf_bits(f0.w);
      a[4]=(short)f2bf_bits(f1.x); a[5]=(short)f2bf_bits(f1.y);
      a[6]=(short)f2bf_bits(f1.z); a[7]=(short)f2bf_bits(f1.w);
      A[rt][kh] = a;
    }
  }
  floatx4 acc[RT][4];
  #pragma unroll
  for (int rt = 0; rt < RT; ++rt)
    #pragma unroll
    for (int ct = 0; ct < 4; ++ct)
      acc[rt][ct] = (floatx4)0.f;
  #pragma unroll
  for (int ct = 0; ct < 4; ++ct) {
    const int coll = wv*64 + ct*16 + ln;
    short8 B0 = *((const short8*)&xT[coll*XT_STRIDE + qd*8]);
    short8 B1 = *((const short8*)&xT[coll*XT_STRIDE + 32 + qd*8]);
    #pragma unroll
    for (int rt = 0; rt < RT; ++rt) {
      acc[rt][ct] = __builtin_amdgcn_mfma_f32_16x16x32_bf16(A[rt][0], B0, acc[rt][ct], 0,0,0);
      acc[rt][ct] = __builtin_amdgcn_mfma_f32_16x16x32_bf16(A[rt][1], B1, acc[rt][ct], 0,0,0);
    }
  }
  float* dst = accum + (size_t)(blockIdx.x & (NBUCK-1))*(2*CO);
  const int bs0 = (col0 + wv*64) >> 5;     // wave covers bs0, bs0+1
  #pragma unroll
  for (int rt = 0; rt < RT; ++rt) {
    float s[4]  = {0.f,0.f,0.f,0.f};
    float sq[4] = {0.f,0.f,0.f,0.f};
    float mxv[2][4];
    #pragma unroll
    for (int h = 0; h < 2; ++h)
      #pragma unroll
      for (int r = 0; r < 4; ++r) mxv[h][r] = -3.402823466e38f;
    #pragma unroll
    for (int ct = 0; ct < 4; ++ct) {
      const int col = col0 + wv*64 + ct*16 + ln;
      #pragma unroll
      for (int r = 0; r < 4; ++r) {
        const int o = rt*16 + qd*4 + r;
        float v = acc[rt][ct][r] + bias_s[o];
        if (!POOL) xout[(size_t)o*NT_COLS + col] = __float2bfloat16(v);
        else mxv[ct>>1][r] = fmaxf(mxv[ct>>1][r], v);
        s[r] += v; sq[r] = fmaf(v, v, sq[r]);
      }
    }
    if (POOL) {
      #pragma unroll
      for (int h = 0; h < 2; ++h) {
        #pragma unroll
        for (int r = 0; r < 4; ++r) {
          float m = mxv[h][r];
          m = fmax_dpp<0x111,0xF,0xF>(m);
          m = fmax_dpp<0x112,0xF,0xF>(m);
          m = fmax_dpp<0x114,0xF,0xF>(m);
          m = fmax_dpp<0x118,0xF,0xF>(m);
          if (ln == 15) {
            const int o = rt*16 + qd*4 + r;
            mx[(size_t)o*(NT_COLS/NK) + bs0 + h] = m;
          }
        }
      }
    }
    #pragma unroll
    for (int r = 0; r < 4; ++r) {
      float a = add16_dpp(s[r]);
      float q = add16_dpp(sq[r]);
      if (ln == 15) {
        const int o = rt*16 + qd*4 + r;
        atomicAdd(&dst[o], a);
        atomicAdd(&dst[CO + o], q);
      }
    }
  }
}

// ---------------- final BN+ReLU on pooled maxes (fp32 out) ------------------
__global__ __launch_bounds__(256) void k_bnmax(const float* __restrict__ mx,
                                               const float* __restrict__ scsh,
                                               float* __restrict__ out1) {
  const int blk = blockIdx.x;        // 16 b x 128 o
  const int o = blk & 127;
  const int b = blk >> 7;
  const float sc = scsh[o], sh = scsh[128+o];
  const int s = threadIdx.x * 4;
  float4 v = *(const float4*)(mx + (size_t)o*(NT_COLS/NK) + b*NS + s);
  float4 r;
  r.x = fmaxf(fmaf(v.x, sc, sh), 0.f);
  r.y = fmaxf(fmaf(v.y, sc, sh), 0.f);
  r.z = fmaxf(fmaf(v.z, sc, sh), 0.f);
  r.w = fmaxf(fmaf(v.w, sc, sh), 0.f);
  *(float4*)(out1 + (size_t)(b*128 + o)*NS + s) = r;
}

extern "C" void kernel_launch(void* const* d_in, const int* in_sizes, int n_in,
                              void* d_out, int out_size, void* d_ws, size_t ws_size,
                              hipStream_t stream) {
  const float* xyz  = (const float*)d_in[0];
  const float* feat = (const float*)d_in[1];
  const float* w0 = (const float*)d_in[2];
  const float* b0 = (const float*)d_in[3];
  const float* g0 = (const float*)d_in[4];
  const float* bt0= (const float*)d_in[5];
  const float* w1 = (const float*)d_in[6];
  const float* b1 = (const float*)d_in[7];
  const float* g1 = (const float*)d_in[8];
  const float* bt1= (const float*)d_in[9];
  const float* w2 = (const float*)d_in[10];
  const float* b2 = (const float*)d_in[11];
  const float* g2 = (const float*)d_in[12];
  const float* bt2= (const float*)d_in[13];

  float* out0 = (float*)d_out;                     // (B,3,NS) fp32
  float* out1 = out0 + (size_t)NB*3*NS;            // (B,128,NS) fp32

  // Workspace (max offset 145,033,216 B ~= 138 MB; ws >= 194 MB proven):
  //   accum@0 (128KB), scsh@131072, newxyz@133120, bidx@329728,
  //   x2@2426880 (64MB), x1@69535744 (64MB), mx3@136644608 (8MB fp32)
  char* ws = (char*)d_ws;
  float* accum  = (float*)(ws + 0);
  float* acc_l1 = accum;                 // NBUCK x 128
  float* acc_l2 = accum + 8192;          // NBUCK x 128
  float* acc_l3 = accum + 16384;         // NBUCK x 256
  float* scsh   = (float*)(ws + 131072);
  float* newxyz = (float*)(ws + 133120);
  int*   bidx   = (int*)  (ws + 329728);
  bf16*  x2     = (bf16*) (ws + 2426880);
  bf16*  x1     = (bf16*) (ws + 69535744);
  float* mx3    = (float*)(ws + 136644608);

  k_zero <<<128, 256, 0, stream>>>(accum);

  k_fps  <<<NB,   256, 0, stream>>>(xyz, newxyz, out0);
  k_ballq<<<16384/4, 256, 0, stream>>>(xyz, newxyz, bidx);
  k_layer1<<<NT_COLS/256, 256, 0, stream>>>(xyz, feat, newxyz, bidx, w0, b0, acc_l1, x1);
  k_finalize<<<1,     256, 0, stream>>>(acc_l1, g0, bt0, scsh + 0, 64);

  k_layerN_mfma<64,false><<<NT_COLS/256, 256, 0, stream>>>(x1, w1, b1, scsh + 0, acc_l2, x2, nullptr);
  k_finalize<<<1,     256, 0, stream>>>(acc_l2, g1, bt1, scsh + 128, 64);

  k_layerN_mfma<128,true><<<NT_COLS/256, 256, 0, stream>>>(x2, w2, b2, scsh + 128, acc_l3, nullptr, mx3);
  k_finalize<<<1,     256, 0, stream>>>(acc_l3, g2, bt2, scsh + 256, 128);

  k_bnmax <<<NB*128, 256, 0, stream>>>(mx3, scsh + 256, out1);
}

// Round 12
// 867.711 us; speedup vs baseline: 1.3117x; 1.2370x over previous
//
#include <hip/hip_runtime.h>
#include <hip/hip_bf16.h>
#include <stdint.h>

#define NB 16
#define NPTS 4096
#define NS 1024
#define NK 32
#define NT_COLS (NB*NS*NK)   // 524288 columns (b*NS+s)*NK + k
#define NBUCK 64             // stat-accumulator buckets

typedef __hip_bfloat16 bf16;
typedef __attribute__((ext_vector_type(8))) short short8;   // 8 bf16 (4 VGPRs)
typedef __attribute__((ext_vector_type(4))) float floatx4;  // MFMA C/D

__device__ __forceinline__ unsigned short f2bf_bits(float v) {
  bf16 b = __float2bfloat16(v);
  return *(unsigned short*)&b;
}

__global__ void k_zero(float* __restrict__ p) {
  p[blockIdx.x*256 + threadIdx.x] = 0.f;
}

// DPP-shifted fmax (verified gfx950 R5/R7/R8). Inactive/OOB src lanes keep old=x.
template<int CTRL, int RM, int BM>
__device__ __forceinline__ float fmax_dpp(float x) {
  int o = __builtin_amdgcn_update_dpp(__float_as_int(x), __float_as_int(x),
                                      CTRL, RM, BM, false);
  return fmaxf(x, __int_as_float(o));
}
// DPP add with zero-fill identity; RM-masked rows add 0 (old=0).
template<int CTRL, int RM>
__device__ __forceinline__ float add_dpp(float x) {
  int o = __builtin_amdgcn_update_dpp(0, __float_as_int(x), CTRL, RM, 0xF, true);
  return __fadd_rn(x, __int_as_float(o));
}
// 16-lane row sum -> lane 15 of each row (mfma C-layout stats).
__device__ __forceinline__ float add16_dpp(float x) {
  x = add_dpp<0x111,0xF>(x); x = add_dpp<0x112,0xF>(x);
  x = add_dpp<0x114,0xF>(x); x = add_dpp<0x118,0xF>(x);
  return x;
}
// full wave64 sum -> lane 63.
__device__ __forceinline__ float add64_dpp(float x) {
  x = add_dpp<0x111,0xF>(x); x = add_dpp<0x112,0xF>(x);
  x = add_dpp<0x114,0xF>(x); x = add_dpp<0x118,0xF>(x);
  x = add_dpp<0x142,0xA>(x);   // row_bcast:15 -> rows 1,3
  x = add_dpp<0x143,0xC>(x);   // row_bcast:31 -> rows 2,3
  return x;
}

// ---------------- FPS: EXACT R8 version (579 us, measured 5x) ---------------
// R6/R10/R11 variants (coord-carry, pk-f32, float4 layout) all regressed;
// this structure is a measured local optimum. Do not modify.
__global__ __launch_bounds__(256) void k_fps(const float* __restrict__ xyz,
                                             float* __restrict__ newxyz,
                                             float* __restrict__ out0) {
  __shared__ float xs[NPTS], ys[NPTS], zs[NPTS];
  __shared__ float selx[NS], sely[NS], selz[NS];
  __shared__ float2 pair[2][4];   // double-buffered (value, idx-bits) per wave
  const int b = blockIdx.x;
  const int t = threadIdx.x;
  const float* p = xyz + (size_t)b * 3 * NPTS;
  for (int i = t; i < NPTS; i += 256) {
    xs[i] = p[i];
    ys[i] = p[NPTS + i];
    zs[i] = p[2*NPTS + i];
  }
  __syncthreads();
  float px[16], py[16], pz[16], dist[16];
  const int p0 = t * 16;
  #pragma unroll
  for (int j = 0; j < 16; ++j) {
    px[j]=xs[p0+j]; py[j]=ys[p0+j]; pz[j]=zs[p0+j]; dist[j]=1e10f;
  }
  const int lane = t & 63, wv = t >> 6;
  int cur = 0;
  for (int i = 0; i < NS; ++i) {
    float cx = xs[cur], cy = ys[cur], cz = zs[cur];
    if (t == 0) { selx[i] = cx; sely[i] = cy; selz[i] = cz; }
    if (i == NS-1) break;
    float bv = -1.0f; int bi = p0;
    #pragma unroll
    for (int j = 0; j < 16; ++j) {
      float dx = __fsub_rn(px[j], cx);
      float dy = __fsub_rn(py[j], cy);
      float dz = __fsub_rn(pz[j], cz);
      float d  = __fadd_rn(__fadd_rn(__fmul_rn(dx,dx), __fmul_rn(dy,dy)), __fmul_rn(dz,dz));
      float nd = fminf(dist[j], d);
      dist[j] = nd;
      if (nd > bv) { bv = nd; bi = p0 + j; }   // strict > => first occurrence
    }
    float x = bv;
    x = fmax_dpp<0x111,0xF,0xF>(x);   // row_shr:1
    x = fmax_dpp<0x112,0xF,0xF>(x);   // row_shr:2
    x = fmax_dpp<0x114,0xF,0xF>(x);   // row_shr:4
    x = fmax_dpp<0x118,0xF,0xF>(x);   // row_shr:8
    x = fmax_dpp<0x142,0xA,0xF>(x);   // row_bcast:15 -> rows 1,3
    x = fmax_dpp<0x143,0xC,0xF>(x);   // row_bcast:31 -> rows 2,3
    float M = __int_as_float(__builtin_amdgcn_readlane(__float_as_int(x), 63));
    unsigned long long mk = __ballot(bv == M);
    int sl  = (int)__builtin_ctzll(mk);
    int wbi = __builtin_amdgcn_readlane(bi, sl);
    if ((t & 63) == 0) pair[i & 1][wv] = make_float2(M, __int_as_float(wbi));
    __syncthreads();
    const float4* pb = (const float4*)&pair[i & 1][0];
    float4 q01 = pb[0], q23 = pb[1];
    float bestv = q01.x; int besti = __float_as_int(q01.y);
    if (q01.z > bestv) { bestv = q01.z; besti = __float_as_int(q01.w); }
    if (q23.x > bestv) { bestv = q23.x; besti = __float_as_int(q23.y); }
    if (q23.z > bestv) { bestv = q23.z; besti = __float_as_int(q23.w); }
    cur = besti;
  }
  __syncthreads();
  for (int i = t; i < NS; i += 256) {
    float vx = selx[i], vy = sely[i], vz = selz[i];
    size_t q = (size_t)b*3*NS + i;
    out0[q] = vx; out0[q + NS] = vy; out0[q + 2*NS] = vz;   // bit-exact copies
    size_t o = (size_t)(b*NS + i)*3;
    newxyz[o] = vx; newxyz[o+1] = vy; newxyz[o+2] = vz;
  }
}

// ---------------- Ball query: one wave per query ----------------------------
__global__ __launch_bounds__(256) void k_ballq(const float* __restrict__ xyz,
                                               const float* __restrict__ newxyz,
                                               int* __restrict__ idx) {
  const int gw = (blockIdx.x * 256 + threadIdx.x) >> 6;
  const int lane = threadIdx.x & 63;
  const int b = gw >> 10;
  const int s = gw & (NS-1);
  const float* xb = xyz + (size_t)b * 3 * NPTS;
  const size_t nq = (size_t)(b*NS + s)*3;
  const float nx = newxyz[nq], ny = newxyz[nq+1], nz = newxyz[nq+2];
  const float sn = __fadd_rn(__fadd_rn(__fmul_rn(nx,nx), __fmul_rn(ny,ny)), __fmul_rn(nz,nz));
  const float R2 = (float)(0.2*0.2);
  int* out = idx + (size_t)gw * NK;
  int cnt = 0, first = 0;
  for (int c0 = 0; c0 < NPTS; c0 += 64) {
    int n = c0 + lane;
    float x = xb[n], y = xb[NPTS+n], z = xb[2*NPTS+n];
    float sx = __fadd_rn(__fadd_rn(__fmul_rn(x,x), __fmul_rn(y,y)), __fmul_rn(z,z));
    float dt = __fadd_rn(__fadd_rn(__fmul_rn(nx,x), __fmul_rn(ny,y)), __fmul_rn(nz,z));
    float sqr = __fsub_rn(__fadd_rn(sn, sx), __fmul_rn(2.0f, dt));
    bool inr = (sqr <= R2);
    unsigned long long m = __ballot(inr);
    if (m != 0ull) {
      if (cnt == 0) first = c0 + (int)__builtin_ctzll(m);
      int rank = __popcll(m & ((1ull << lane) - 1ull));
      int pos = cnt + rank;
      if (inr && pos < NK) out[pos] = n;
      cnt += __popcll(m);
      if (cnt >= NK) break;
    }
  }
  int tot = cnt < NK ? cnt : NK;
  if (lane >= tot && lane < NK) out[lane] = first;
}

// ---------------- Moments: S = sum u (6), M = sum u u^T (21) ----------------
// Layer-1 stats are LINEAR in the gathered input u (no relu before BN):
//   sum x1[o]   = w0[o].S + N b0[o]
//   sum x1[o]^2 = w0[o]^T M w0[o] + 2 b0[o] (w0[o].S) + N b0[o]^2
// so one 27-float reduction replaces the whole x1 materialization.
__global__ __launch_bounds__(256) void k_moments(const float* __restrict__ xyz,
                                                 const float* __restrict__ feat,
                                                 const float* __restrict__ newxyz,
                                                 const int* __restrict__ idx,
                                                 float* __restrict__ accum) {
  const int t = threadIdx.x;
  float S[6] = {0,0,0,0,0,0};
  float Mm[21];
  #pragma unroll
  for (int k = 0; k < 21; ++k) Mm[k] = 0.f;
  for (int it = 0; it < 8; ++it) {
    const int col = blockIdx.x*2048 + it*256 + t;
    const int bs = col >> 5;
    const int b  = bs >> 10;
    const int n  = idx[col];
    const float* xb = xyz  + (size_t)b*3*NPTS;
    const float* fb = feat + (size_t)b*3*NPTS;
    float u[6];
    u[0] = __fsub_rn(xb[n],        newxyz[(size_t)bs*3]);
    u[1] = __fsub_rn(xb[NPTS+n],   newxyz[(size_t)bs*3+1]);
    u[2] = __fsub_rn(xb[2*NPTS+n], newxyz[(size_t)bs*3+2]);
    u[3] = fb[n];
    u[4] = fb[NPTS+n];
    u[5] = fb[2*NPTS+n];
    int k = 0;
    #pragma unroll
    for (int i = 0; i < 6; ++i) {
      S[i] += u[i];
      #pragma unroll
      for (int j = i; j < 6; ++j) { Mm[k] = fmaf(u[i], u[j], Mm[k]); ++k; }
    }
  }
  const int lane = t & 63;
  float* dst = accum + (size_t)(blockIdx.x & (NBUCK-1))*32;   // 27 used of 32
  #pragma unroll
  for (int i = 0; i < 6; ++i) {
    float s = add64_dpp(S[i]);
    if (lane == 63) atomicAdd(&dst[i], s);
  }
  #pragma unroll
  for (int k = 0; k < 21; ++k) {
    float m = add64_dpp(Mm[k]);
    if (lane == 63) atomicAdd(&dst[6+k], m);
  }
}

// ---------------- finalize layer-1 BN from moments (closed form) ------------
__global__ void k_finalize1(const float* __restrict__ accum,
                            const float* __restrict__ w0, const float* __restrict__ b0,
                            const float* __restrict__ g, const float* __restrict__ beta,
                            float* __restrict__ scsh) {
  __shared__ float Sm[27];
  const int t = threadIdx.x;
  if (t < 27) {
    float s = 0.f;
    for (int bkt = 0; bkt < NBUCK; ++bkt) s += accum[(size_t)bkt*32 + t];
    Sm[t] = s;
  }
  __syncthreads();
  if (t < 64) {
    const float* w = w0 + t*6;
    const float b = b0[t];
    float ws = 0.f;
    #pragma unroll
    for (int i = 0; i < 6; ++i) ws = fmaf(w[i], Sm[i], ws);
    float quad = 0.f;
    int k = 6;
    #pragma unroll
    for (int i = 0; i < 6; ++i) {
      #pragma unroll
      for (int j = i; j < 6; ++j) {
        float c = w[i]*w[j];
        if (j > i) c *= 2.f;
        quad = fmaf(c, Sm[k], quad);
        ++k;
      }
    }
    const float n = (float)NT_COLS;
    float mean = (ws + n*b) / n;
    float ex2  = (quad + 2.f*b*ws + n*b*b) / n;
    float var  = ex2 - mean*mean;
    if (var < 0.f) var = 0.f;
    float rs = rsqrtf(var + 1e-5f);
    float sc = g[t] * rs;
    scsh[t]    = sc;
    scsh[64+t] = beta[t] - mean * sc;
  }
}

// ---------------- generic bucket finalize (layers 2/3) ----------------------
__global__ void k_finalize(const float* __restrict__ accum,
                           const float* __restrict__ g, const float* __restrict__ beta,
                           float* __restrict__ scsh, int C) {
  int o = threadIdx.x;
  if (o < C) {
    float s = 0.f, ss = 0.f;
    for (int bkt = 0; bkt < NBUCK; ++bkt) {
      s  += accum[(size_t)bkt*(2*C) + o];
      ss += accum[(size_t)bkt*(2*C) + C + o];
    }
    const float n = (float)NT_COLS;
    float mu  = s / n;
    float var = ss / n - mu*mu;
    if (var < 0.f) var = 0.f;
    float rs = rsqrtf(var + 1e-5f);
    float sc = g[o] * rs;
    scsh[o]   = sc;
    scsh[C+o] = beta[o] - mu * sc;
  }
}

#define XT_STRIDE 72   // bf16 elems; 144 B row -> b128-aligned

// ---------------- Layer 2: recompute-x1 staging + MFMA + fused stats --------
// x1 never materialized: staging gathers inputs (L2-resident, 1.5 MB),
// computes the 6->64 conv per column, applies BN1+ReLU, packs bf16 into LDS.
__global__ __launch_bounds__(256) void k_layer2_mfma(
    const float* __restrict__ xyz,
    const float* __restrict__ feat,
    const float* __restrict__ newxyz,
    const int*   __restrict__ idx,
    const float* __restrict__ w0g,   // [64][6]
    const float* __restrict__ b0g,   // [64]
    const float* __restrict__ w1,    // [64][64]
    const float* __restrict__ b1,    // [64]
    const float* __restrict__ scsh,  // sc1[64], sh1[64]
    float*       __restrict__ accum, // [NBUCK][128]
    bf16*        __restrict__ x2) {  // [64][NT_COLS]
  __shared__ short xT[256*XT_STRIDE];
  __shared__ float w0s[64*6];
  __shared__ float b0s[64];
  __shared__ float sc_s[64], sh_s[64], bias_s[64];
  const int t = threadIdx.x;
  const int col0 = blockIdx.x * 256;
  for (int i = t; i < 64*6; i += 256) w0s[i] = w0g[i];
  if (t < 64) {
    b0s[t] = b0g[t];
    sc_s[t] = scsh[t]; sh_s[t] = scsh[64+t];
    bias_s[t] = b1[t];
  }
  __syncthreads();
  {
    const int col = col0 + t;
    const int bs = col >> 5;
    const int b  = bs >> 10;
    const int n  = idx[col];
    const float* xb = xyz  + (size_t)b*3*NPTS;
    const float* fb = feat + (size_t)b*3*NPTS;
    float u[6];
    u[0] = __fsub_rn(xb[n],        newxyz[(size_t)bs*3]);
    u[1] = __fsub_rn(xb[NPTS+n],   newxyz[(size_t)bs*3+1]);
    u[2] = __fsub_rn(xb[2*NPTS+n], newxyz[(size_t)bs*3+2]);
    u[3] = fb[n];
    u[4] = fb[NPTS+n];
    u[5] = fb[2*NPTS+n];
    #pragma unroll
    for (int c0 = 0; c0 < 64; c0 += 8) {
      short8 pk;
      #pragma unroll
      for (int j = 0; j < 8; ++j) {
        const int o = c0 + j;
        float v = b0s[o];
        #pragma unroll
        for (int c = 0; c < 6; ++c) v = fmaf(u[c], w0s[o*6+c], v);
        v = fmaxf(fmaf(v, sc_s[o], sh_s[o]), 0.f);   // BN1 + ReLU
        pk[j] = (short)f2bf_bits(v);
      }
      *((short8*)&xT[t*XT_STRIDE + c0]) = pk;
    }
  }
  __syncthreads();
  const int lane = t & 63, wv = t >> 6;
  const int qd = lane >> 4, ln = lane & 15;
  short8 A[4][2];
  #pragma unroll
  for (int rt = 0; rt < 4; ++rt) {
    #pragma unroll
    for (int kh = 0; kh < 2; ++kh) {
      const float* wp = w1 + (size_t)(rt*16 + ln)*64 + kh*32 + qd*8;
      float4 f0 = *(const float4*)wp;
      float4 f1 = *(const float4*)(wp + 4);
      short8 a;
      a[0]=(short)f2bf_bits(f0.x); a[1]=(short)f2bf_bits(f0.y);
      a[2]=(short)f2bf_bits(f0.z); a[3]=(short)f2bf_bits(f0.w);
      a[4]=(short)f2bf_bits(f1.x); a[5]=(short)f2bf_bits(f1.y);
      a[6]=(short)f2bf_bits(f1.z); a[7]=(short)f2bf_bits(f1.w);
      A[rt][kh] = a;
    }
  }
  floatx4 acc[4][4];
  #pragma unroll
  for (int rt = 0; rt < 4; ++rt)
    #pragma unroll
    for (int ct = 0; ct < 4; ++ct)
      acc[rt][ct] = (floatx4)0.f;
  #pragma unroll
  for (int ct = 0; ct < 4; ++ct) {
    const int coll = wv*64 + ct*16 + ln;
    short8 B0 = *((const short8*)&xT[coll*XT_STRIDE + qd*8]);
    short8 B1 = *((const short8*)&xT[coll*XT_STRIDE + 32 + qd*8]);
    #pragma unroll
    for (int rt = 0; rt < 4; ++rt) {
      acc[rt][ct] = __builtin_amdgcn_mfma_f32_16x16x32_bf16(A[rt][0], B0, acc[rt][ct], 0,0,0);
      acc[rt][ct] = __builtin_amdgcn_mfma_f32_16x16x32_bf16(A[rt][1], B1, acc[rt][ct], 0,0,0);
    }
  }
  float* dst = accum + (size_t)(blockIdx.x & (NBUCK-1))*128;
  #pragma unroll
  for (int rt = 0; rt < 4; ++rt) {
    float s[4]  = {0.f,0.f,0.f,0.f};
    float sq[4] = {0.f,0.f,0.f,0.f};
    #pragma unroll
    for (int ct = 0; ct < 4; ++ct) {
      const int col = col0 + wv*64 + ct*16 + ln;
      #pragma unroll
      for (int r = 0; r < 4; ++r) {
        const int o = rt*16 + qd*4 + r;
        float v = acc[rt][ct][r] + bias_s[o];
        x2[(size_t)o*NT_COLS + col] = __float2bfloat16(v);
        s[r] += v; sq[r] = fmaf(v, v, sq[r]);
      }
    }
    #pragma unroll
    for (int r = 0; r < 4; ++r) {
      float a = add16_dpp(s[r]);
      float q = add16_dpp(sq[r]);
      if (ln == 15) {
        const int o = rt*16 + qd*4 + r;
        atomicAdd(&dst[o], a);
        atomicAdd(&dst[64 + o], q);
      }
    }
  }
}

// ---------------- Layer 3: MFMA + fused stats + fused max-pool --------------
__global__ __launch_bounds__(256) void k_layer3_mfma(
    const bf16*  __restrict__ xin,   // [64][NT_COLS] = x2
    const float* __restrict__ wN,    // [128][64]
    const float* __restrict__ bN,    // [128]
    const float* __restrict__ scsh,  // sc2[64], sh2[64]
    float*       __restrict__ accum, // [NBUCK][256]
    float*       __restrict__ mx) {  // [128][NT_COLS/NK]
  constexpr int CO = 128, RT = CO/16;
  __shared__ short xT[256*XT_STRIDE];
  __shared__ float sc_s[64], sh_s[64], bias_s[CO];
  const int t = threadIdx.x;
  const int col0 = blockIdx.x * 256;
  if (t < 64) { sc_s[t] = scsh[t]; sh_s[t] = scsh[64+t]; }
  if (t < CO) bias_s[t] = bN[t];
  __syncthreads();
  {
    const int col = col0 + t;
    #pragma unroll
    for (int c0 = 0; c0 < 64; c0 += 8) {
      short8 pk;
      #pragma unroll
      for (int j = 0; j < 8; ++j) {
        float v = __bfloat162float(xin[(size_t)(c0+j)*NT_COLS + col]);
        v = fmaxf(fmaf(v, sc_s[c0+j], sh_s[c0+j]), 0.f);
        pk[j] = (short)f2bf_bits(v);
      }
      *((short8*)&xT[t*XT_STRIDE + c0]) = pk;
    }
  }
  __syncthreads();
  const int lane = t & 63, wv = t >> 6;
  const int qd = lane >> 4, ln = lane & 15;
  short8 A[RT][2];
  #pragma unroll
  for (int rt = 0; rt < RT; ++rt) {
    #pragma unroll
    for (int kh = 0; kh < 2; ++kh) {
      const float* wp = wN + (size_t)(rt*16 + ln)*64 + kh*32 + qd*8;
      float4 f0 = *(const float4*)wp;
      float4 f1 = *(const float4*)(wp + 4);
      short8 a;
      a[0]=(short)f2bf_bits(f0.x); a[1]=(short)f2bf_bits(f0.y);
      a[2]=(short)f2bf_bits(f0.z); a[3]=(short)f2bf_bits(f0.w);
      a[4]=(short)f2bf_bits(f1.x); a[5]=(short)f2bf_bits(f1.y);
      a[6]=(short)f2bf_bits(f1.z); a[7]=(short)f2bf_bits(f1.w);
      A[rt][kh] = a;
    }
  }
  floatx4 acc[RT][4];
  #pragma unroll
  for (int rt = 0; rt < RT; ++rt)
    #pragma unroll
    for (int ct = 0; ct < 4; ++ct)
      acc[rt][ct] = (floatx4)0.f;
  #pragma unroll
  for (int ct = 0; ct < 4; ++ct) {
    const int coll = wv*64 + ct*16 + ln;
    short8 B0 = *((const short8*)&xT[coll*XT_STRIDE + qd*8]);
    short8 B1 = *((const short8*)&xT[coll*XT_STRIDE + 32 + qd*8]);
    #pragma unroll
    for (int rt = 0; rt < RT; ++rt) {
      acc[rt][ct] = __builtin_amdgcn_mfma_f32_16x16x32_bf16(A[rt][0], B0, acc[rt][ct], 0,0,0);
      acc[rt][ct] = __builtin_amdgcn_mfma_f32_16x16x32_bf16(A[rt][1], B1, acc[rt][ct], 0,0,0);
    }
  }
  float* dst = accum + (size_t)(blockIdx.x & (NBUCK-1))*(2*CO);
  const int bs0 = (col0 + wv*64) >> 5;     // wave covers bs0, bs0+1
  #pragma unroll
  for (int rt = 0; rt < RT; ++rt) {
    float s[4]  = {0.f,0.f,0.f,0.f};
    float sq[4] = {0.f,0.f,0.f,0.f};
    float mxv[2][4];
    #pragma unroll
    for (int h = 0; h < 2; ++h)
      #pragma unroll
      for (int r = 0; r < 4; ++r) mxv[h][r] = -3.402823466e38f;
    #pragma unroll
    for (int ct = 0; ct < 4; ++ct) {
      #pragma unroll
      for (int r = 0; r < 4; ++r) {
        const int o = rt*16 + qd*4 + r;
        float v = acc[rt][ct][r] + bias_s[o];
        mxv[ct>>1][r] = fmaxf(mxv[ct>>1][r], v);
        s[r] += v; sq[r] = fmaf(v, v, sq[r]);
      }
    }
    #pragma unroll
    for (int h = 0; h < 2; ++h) {
      #pragma unroll
      for (int r = 0; r < 4; ++r) {
        float m = mxv[h][r];
        m = fmax_dpp<0x111,0xF,0xF>(m);
        m = fmax_dpp<0x112,0xF,0xF>(m);
        m = fmax_dpp<0x114,0xF,0xF>(m);
        m = fmax_dpp<0x118,0xF,0xF>(m);
        if (ln == 15) {
          const int o = rt*16 + qd*4 + r;
          mx[(size_t)o*(NT_COLS/NK) + bs0 + h] = m;
        }
      }
    }
    #pragma unroll
    for (int r = 0; r < 4; ++r) {
      float a = add16_dpp(s[r]);
      float q = add16_dpp(sq[r]);
      if (ln == 15) {
        const int o = rt*16 + qd*4 + r;
        atomicAdd(&dst[o], a);
        atomicAdd(&dst[CO + o], q);
      }
    }
  }
}

// ---------------- final BN+ReLU on pooled maxes (fp32 out) ------------------
__global__ __launch_bounds__(256) void k_bnmax(const float* __restrict__ mx,
                                               const float* __restrict__ scsh,
                                               float* __restrict__ out1) {
  const int blk = blockIdx.x;        // 16 b x 128 o
  const int o = blk & 127;
  const int b = blk >> 7;
  const float sc = scsh[o], sh = scsh[128+o];
  const int s = threadIdx.x * 4;
  float4 v = *(const float4*)(mx + (size_t)o*(NT_COLS/NK) + b*NS + s);
  float4 r;
  r.x = fmaxf(fmaf(v.x, sc, sh), 0.f);
  r.y = fmaxf(fmaf(v.y, sc, sh), 0.f);
  r.z = fmaxf(fmaf(v.z, sc, sh), 0.f);
  r.w = fmaxf(fmaf(v.w, sc, sh), 0.f);
  *(float4*)(out1 + (size_t)(b*128 + o)*NS + s) = r;
}

extern "C" void kernel_launch(void* const* d_in, const int* in_sizes, int n_in,
                              void* d_out, int out_size, void* d_ws, size_t ws_size,
                              hipStream_t stream) {
  const float* xyz  = (const float*)d_in[0];
  const float* feat = (const float*)d_in[1];
  const float* w0 = (const float*)d_in[2];
  const float* b0 = (const float*)d_in[3];
  const float* g0 = (const float*)d_in[4];
  const float* bt0= (const float*)d_in[5];
  const float* w1 = (const float*)d_in[6];
  const float* b1 = (const float*)d_in[7];
  const float* g1 = (const float*)d_in[8];
  const float* bt1= (const float*)d_in[9];
  const float* w2 = (const float*)d_in[10];
  const float* b2 = (const float*)d_in[11];
  const float* g2 = (const float*)d_in[12];
  const float* bt2= (const float*)d_in[13];

  float* out0 = (float*)d_out;                     // (B,3,NS) fp32
  float* out1 = out0 + (size_t)NB*3*NS;            // (B,128,NS) fp32

  // Workspace (max offset ~138 MB; ws >= 194 MB proven):
  //   accum@0 (128KB: l1-moments NBUCKx32, l2 @+8192 NBUCKx128, l3 @+16384 NBUCKx256)
  //   scsh@131072 (l1:0, l2:128, l3:256), newxyz@133120, bidx@329728,
  //   x2@2426880 (64MB), mx3@136644608 (8MB fp32). x1 is GONE (moments trick).
  char* ws = (char*)d_ws;
  float* accum  = (float*)(ws + 0);
  float* acc_l1 = accum;                 // NBUCK x 32 (27 used: S6 + M21)
  float* acc_l2 = accum + 8192;          // NBUCK x 128
  float* acc_l3 = accum + 16384;         // NBUCK x 256
  float* scsh   = (float*)(ws + 131072);
  float* newxyz = (float*)(ws + 133120);
  int*   bidx   = (int*)  (ws + 329728);
  bf16*  x2     = (bf16*) (ws + 2426880);
  float* mx3    = (float*)(ws + 136644608);

  k_zero <<<128, 256, 0, stream>>>(accum);

  k_fps  <<<NB,   256, 0, stream>>>(xyz, newxyz, out0);
  k_ballq<<<16384/4, 256, 0, stream>>>(xyz, newxyz, bidx);

  k_moments  <<<256, 256, 0, stream>>>(xyz, feat, newxyz, bidx, acc_l1);
  k_finalize1<<<1,    64, 0, stream>>>(acc_l1, w0, b0, g0, bt0, scsh + 0);

  k_layer2_mfma<<<NT_COLS/256, 256, 0, stream>>>(xyz, feat, newxyz, bidx,
                                                 w0, b0, w1, b1, scsh + 0,
                                                 acc_l2, x2);
  k_finalize<<<1, 256, 0, stream>>>(acc_l2, g1, bt1, scsh + 128, 64);

  k_layer3_mfma<<<NT_COLS/256, 256, 0, stream>>>(x2, w2, b2, scsh + 128,
                                                 acc_l3, mx3);
  k_finalize<<<1, 256, 0, stream>>>(acc_l3, g2, bt2, scsh + 256, 128);

  k_bnmax <<<NB*128, 256, 0, stream>>>(mx3, scsh + 256, out1);
}

// Round 14
// 837.032 us; speedup vs baseline: 1.3598x; 1.0367x over previous
//
#include <hip/hip_runtime.h>
#include <hip/hip_bf16.h>
#include <stdint.h>

#define NB 16
#define NPTS 4096
#define NS 1024
#define NK 32
#define NT_COLS (NB*NS*NK)   // 524288 columns (b*NS+s)*NK + k
#define NBUCK 64             // stat-accumulator buckets

typedef __hip_bfloat16 bf16;
typedef __attribute__((ext_vector_type(8))) short short8;   // 8 bf16 (4 VGPRs)
typedef __attribute__((ext_vector_type(4))) float floatx4;  // MFMA C/D

__device__ __forceinline__ unsigned short f2bf_bits(float v) {
  bf16 b = __float2bfloat16(v);
  return *(unsigned short*)&b;
}

// DPP-shifted fmax (verified gfx950 R5/R7/R8). Inactive/OOB src lanes keep old=x.
template<int CTRL, int RM, int BM>
__device__ __forceinline__ float fmax_dpp(float x) {
  int o = __builtin_amdgcn_update_dpp(__float_as_int(x), __float_as_int(x),
                                      CTRL, RM, BM, false);
  return fmaxf(x, __int_as_float(o));
}
// DPP add with zero-fill identity; RM-masked rows add 0 (old=0).
template<int CTRL, int RM>
__device__ __forceinline__ float add_dpp(float x) {
  int o = __builtin_amdgcn_update_dpp(0, __float_as_int(x), CTRL, RM, 0xF, true);
  return __fadd_rn(x, __int_as_float(o));
}
// 16-lane row sum -> lane 15 of each row (mfma C-layout stats).
__device__ __forceinline__ float add16_dpp(float x) {
  x = add_dpp<0x111,0xF>(x); x = add_dpp<0x112,0xF>(x);
  x = add_dpp<0x114,0xF>(x); x = add_dpp<0x118,0xF>(x);
  return x;
}
// full wave64 sum -> lane 63.
__device__ __forceinline__ float add64_dpp(float x) {
  x = add_dpp<0x111,0xF>(x); x = add_dpp<0x112,0xF>(x);
  x = add_dpp<0x114,0xF>(x); x = add_dpp<0x118,0xF>(x);
  x = add_dpp<0x142,0xA>(x);   // row_bcast:15 -> rows 1,3
  x = add_dpp<0x143,0xC>(x);   // row_bcast:31 -> rows 2,3
  return x;
}

// ---------------- FPS: EXACT R8 structure (579us, 5x measured) --------------
// + cheap prologue: zeros the 128KB accum region (replaces k_zero launch).
// R6/R9/R10/R11 loop variants all regressed; do not modify the iteration.
__global__ __launch_bounds__(256) void k_fps(const float* __restrict__ xyz,
                                             float* __restrict__ newxyz,
                                             float* __restrict__ out0,
                                             float* __restrict__ zero_region) {
  const int b = blockIdx.x;
  const int t = threadIdx.x;
  {
    float* zp = zero_region + (size_t)b*2048 + t;
    #pragma unroll
    for (int j = 0; j < 8; ++j) zp[j*256] = 0.f;
  }
  __shared__ float xs[NPTS], ys[NPTS], zs[NPTS];
  __shared__ float selx[NS], sely[NS], selz[NS];
  __shared__ float2 pair[2][4];   // double-buffered (value, idx-bits) per wave
  const float* p = xyz + (size_t)b * 3 * NPTS;
  for (int i = t; i < NPTS; i += 256) {
    xs[i] = p[i];
    ys[i] = p[NPTS + i];
    zs[i] = p[2*NPTS + i];
  }
  __syncthreads();
  float px[16], py[16], pz[16], dist[16];
  const int p0 = t * 16;
  #pragma unroll
  for (int j = 0; j < 16; ++j) {
    px[j]=xs[p0+j]; py[j]=ys[p0+j]; pz[j]=zs[p0+j]; dist[j]=1e10f;
  }
  const int lane = t & 63, wv = t >> 6;
  int cur = 0;
  for (int i = 0; i < NS; ++i) {
    float cx = xs[cur], cy = ys[cur], cz = zs[cur];
    if (t == 0) { selx[i] = cx; sely[i] = cy; selz[i] = cz; }
    if (i == NS-1) break;
    float bv = -1.0f; int bi = p0;
    #pragma unroll
    for (int j = 0; j < 16; ++j) {
      float dx = __fsub_rn(px[j], cx);
      float dy = __fsub_rn(py[j], cy);
      float dz = __fsub_rn(pz[j], cz);
      float d  = __fadd_rn(__fadd_rn(__fmul_rn(dx,dx), __fmul_rn(dy,dy)), __fmul_rn(dz,dz));
      float nd = fminf(dist[j], d);
      dist[j] = nd;
      if (nd > bv) { bv = nd; bi = p0 + j; }   // strict > => first occurrence
    }
    float x = bv;
    x = fmax_dpp<0x111,0xF,0xF>(x);   // row_shr:1
    x = fmax_dpp<0x112,0xF,0xF>(x);   // row_shr:2
    x = fmax_dpp<0x114,0xF,0xF>(x);   // row_shr:4
    x = fmax_dpp<0x118,0xF,0xF>(x);   // row_shr:8
    x = fmax_dpp<0x142,0xA,0xF>(x);   // row_bcast:15 -> rows 1,3
    x = fmax_dpp<0x143,0xC,0xF>(x);   // row_bcast:31 -> rows 2,3
    float M = __int_as_float(__builtin_amdgcn_readlane(__float_as_int(x), 63));
    unsigned long long mk = __ballot(bv == M);
    int sl  = (int)__builtin_ctzll(mk);
    int wbi = __builtin_amdgcn_readlane(bi, sl);
    if ((t & 63) == 0) pair[i & 1][wv] = make_float2(M, __int_as_float(wbi));
    __syncthreads();
    const float4* pb = (const float4*)&pair[i & 1][0];
    float4 q01 = pb[0], q23 = pb[1];
    float bestv = q01.x; int besti = __float_as_int(q01.y);
    if (q01.z > bestv) { bestv = q01.z; besti = __float_as_int(q01.w); }
    if (q23.x > bestv) { bestv = q23.x; besti = __float_as_int(q23.y); }
    if (q23.z > bestv) { bestv = q23.z; besti = __float_as_int(q23.w); }
    cur = besti;
  }
  __syncthreads();
  for (int i = t; i < NS; i += 256) {
    float vx = selx[i], vy = sely[i], vz = selz[i];
    size_t q = (size_t)b*3*NS + i;
    out0[q] = vx; out0[q + NS] = vy; out0[q + 2*NS] = vz;   // bit-exact copies
    size_t o = (size_t)(b*NS + i)*3;
    newxyz[o] = vx; newxyz[o+1] = vy; newxyz[o+2] = vz;
  }
}

// ---------------- Ball query: LDS-staged points, 4 queries/block ------------
// Per-query arithmetic and ballot order bit-identical to the R8 version.
__global__ __launch_bounds__(256) void k_ballq(const float* __restrict__ xyz,
                                               const float* __restrict__ newxyz,
                                               int* __restrict__ idx) {
  __shared__ float xs[NPTS], ys[NPTS], zs[NPTS];
  const int b  = blockIdx.x >> 8;                 // 256 blocks per batch
  const int s  = (blockIdx.x & 255) * 4 + (threadIdx.x >> 6);
  const int lane = threadIdx.x & 63;
  const float* p = xyz + (size_t)b * 3 * NPTS;
  for (int i = threadIdx.x; i < NPTS; i += 256) {
    xs[i] = p[i];
    ys[i] = p[NPTS + i];
    zs[i] = p[2*NPTS + i];
  }
  __syncthreads();
  const size_t nq = (size_t)(b*NS + s)*3;
  const float nx = newxyz[nq], ny = newxyz[nq+1], nz = newxyz[nq+2];
  const float sn = __fadd_rn(__fadd_rn(__fmul_rn(nx,nx), __fmul_rn(ny,ny)), __fmul_rn(nz,nz));
  const float R2 = (float)(0.2*0.2);
  int* out = idx + (size_t)(b*NS + s) * NK;
  int cnt = 0, first = 0;
  for (int c0 = 0; c0 < NPTS; c0 += 64) {
    int n = c0 + lane;
    float x = xs[n], y = ys[n], z = zs[n];
    float sx = __fadd_rn(__fadd_rn(__fmul_rn(x,x), __fmul_rn(y,y)), __fmul_rn(z,z));
    float dt = __fadd_rn(__fadd_rn(__fmul_rn(nx,x), __fmul_rn(ny,y)), __fmul_rn(nz,z));
    float sqr = __fsub_rn(__fadd_rn(sn, sx), __fmul_rn(2.0f, dt));
    bool inr = (sqr <= R2);
    unsigned long long m = __ballot(inr);
    if (m != 0ull) {
      if (cnt == 0) first = c0 + (int)__builtin_ctzll(m);
      int rank = __popcll(m & ((1ull << lane) - 1ull));
      int pos = cnt + rank;
      if (inr && pos < NK) out[pos] = n;
      cnt += __popcll(m);
      if (cnt >= NK) break;
    }
  }
  int tot = cnt < NK ? cnt : NK;
  if (lane >= tot && lane < NK) out[lane] = first;
}

// ---------------- Moments: S = sum u (6), M = sum u u^T (21) ----------------
// Layer-1 stats are LINEAR in the gathered input u (no relu before BN).
// NOTE (R13 post-mortem): fusing the finalize into producers via a last-block
// ticket broke numerics (ticket race without pre-syncthreads + cross-XCD L2
// visibility of plain accum reads). Separate finalize kernels are the proven
// form — kernel boundaries provide the needed coherence. Do not re-fuse.
__global__ __launch_bounds__(256) void k_moments(const float* __restrict__ xyz,
                                                 const float* __restrict__ feat,
                                                 const float* __restrict__ newxyz,
                                                 const int* __restrict__ idx,
                                                 float* __restrict__ accum) {
  const int t = threadIdx.x;
  float S[6] = {0,0,0,0,0,0};
  float Mm[21];
  #pragma unroll
  for (int k = 0; k < 21; ++k) Mm[k] = 0.f;
  for (int it = 0; it < 8; ++it) {
    const int col = blockIdx.x*2048 + it*256 + t;
    const int bs = col >> 5;
    const int b  = bs >> 10;
    const int n  = idx[col];
    const float* xb = xyz  + (size_t)b*3*NPTS;
    const float* fb = feat + (size_t)b*3*NPTS;
    float u[6];
    u[0] = __fsub_rn(xb[n],        newxyz[(size_t)bs*3]);
    u[1] = __fsub_rn(xb[NPTS+n],   newxyz[(size_t)bs*3+1]);
    u[2] = __fsub_rn(xb[2*NPTS+n], newxyz[(size_t)bs*3+2]);
    u[3] = fb[n];
    u[4] = fb[NPTS+n];
    u[5] = fb[2*NPTS+n];
    int k = 0;
    #pragma unroll
    for (int i = 0; i < 6; ++i) {
      S[i] += u[i];
      #pragma unroll
      for (int j = i; j < 6; ++j) { Mm[k] = fmaf(u[i], u[j], Mm[k]); ++k; }
    }
  }
  const int lane = t & 63;
  float* dst = accum + (size_t)(blockIdx.x & (NBUCK-1))*32;   // 27 used of 32
  #pragma unroll
  for (int i = 0; i < 6; ++i) {
    float s = add64_dpp(S[i]);
    if (lane == 63) atomicAdd(&dst[i], s);
  }
  #pragma unroll
  for (int k = 0; k < 21; ++k) {
    float m = add64_dpp(Mm[k]);
    if (lane == 63) atomicAdd(&dst[6+k], m);
  }
}

// ---------------- finalize layer-1 BN from moments (closed form) ------------
__global__ void k_finalize1(const float* __restrict__ accum,
                            const float* __restrict__ w0, const float* __restrict__ b0,
                            const float* __restrict__ g, const float* __restrict__ beta,
                            float* __restrict__ scsh) {
  __shared__ float Sm[27];
  const int t = threadIdx.x;
  if (t < 27) {
    float s = 0.f;
    for (int bkt = 0; bkt < NBUCK; ++bkt) s += accum[(size_t)bkt*32 + t];
    Sm[t] = s;
  }
  __syncthreads();
  if (t < 64) {
    const float* w = w0 + t*6;
    const float b = b0[t];
    float ws = 0.f;
    #pragma unroll
    for (int i = 0; i < 6; ++i) ws = fmaf(w[i], Sm[i], ws);
    float quad = 0.f;
    int k = 6;
    #pragma unroll
    for (int i = 0; i < 6; ++i) {
      #pragma unroll
      for (int j = i; j < 6; ++j) {
        float c = w[i]*w[j];
        if (j > i) c *= 2.f;
        quad = fmaf(c, Sm[k], quad);
        ++k;
      }
    }
    const float n = (float)NT_COLS;
    float mean = (ws + n*b) / n;
    float ex2  = (quad + 2.f*b*ws + n*b*b) / n;
    float var  = ex2 - mean*mean;
    if (var < 0.f) var = 0.f;
    float rs = rsqrtf(var + 1e-5f);
    float sc = g[t] * rs;
    scsh[t]    = sc;
    scsh[64+t] = beta[t] - mean * sc;
  }
}

// ---------------- generic bucket finalize (layers 2/3) ----------------------
__global__ void k_finalize(const float* __restrict__ accum,
                           const float* __restrict__ g, const float* __restrict__ beta,
                           float* __restrict__ scsh, int C) {
  int o = threadIdx.x;
  if (o < C) {
    float s = 0.f, ss = 0.f;
    for (int bkt = 0; bkt < NBUCK; ++bkt) {
      s  += accum[(size_t)bkt*(2*C) + o];
      ss += accum[(size_t)bkt*(2*C) + C + o];
    }
    const float n = (float)NT_COLS;
    float mu  = s / n;
    float var = ss / n - mu*mu;
    if (var < 0.f) var = 0.f;
    float rs = rsqrtf(var + 1e-5f);
    float sc = g[o] * rs;
    scsh[o]   = sc;
    scsh[C+o] = beta[o] - mu * sc;
  }
}

#define XT_STRIDE 72   // bf16 elems; 144 B row -> b128-aligned

// ---------------- Layer 2: recompute-x1 staging + MFMA + fused stats --------
// x1 never materialized (moments trick).
__global__ __launch_bounds__(256) void k_layer2_mfma(
    const float* __restrict__ xyz,
    const float* __restrict__ feat,
    const float* __restrict__ newxyz,
    const int*   __restrict__ idx,
    const float* __restrict__ w0g,   // [64][6]
    const float* __restrict__ b0g,   // [64]
    const float* __restrict__ w1,    // [64][64]
    const float* __restrict__ b1,    // [64]
    const float* __restrict__ scsh,  // sc1[64], sh1[64]
    float*       __restrict__ accum, // [NBUCK][128]
    bf16*        __restrict__ x2) {  // [64][NT_COLS]
  __shared__ short xT[256*XT_STRIDE];
  __shared__ float w0s[64*6];
  __shared__ float b0s[64];
  __shared__ float sc_s[64], sh_s[64], bias_s[64];
  const int t = threadIdx.x;
  const int col0 = blockIdx.x * 256;
  for (int i = t; i < 64*6; i += 256) w0s[i] = w0g[i];
  if (t < 64) {
    b0s[t] = b0g[t];
    sc_s[t] = scsh[t]; sh_s[t] = scsh[64+t];
    bias_s[t] = b1[t];
  }
  __syncthreads();
  {
    const int col = col0 + t;
    const int bs = col >> 5;
    const int b  = bs >> 10;
    const int n  = idx[col];
    const float* xb = xyz  + (size_t)b*3*NPTS;
    const float* fb = feat + (size_t)b*3*NPTS;
    float u[6];
    u[0] = __fsub_rn(xb[n],        newxyz[(size_t)bs*3]);
    u[1] = __fsub_rn(xb[NPTS+n],   newxyz[(size_t)bs*3+1]);
    u[2] = __fsub_rn(xb[2*NPTS+n], newxyz[(size_t)bs*3+2]);
    u[3] = fb[n];
    u[4] = fb[NPTS+n];
    u[5] = fb[2*NPTS+n];
    #pragma unroll
    for (int c0 = 0; c0 < 64; c0 += 8) {
      short8 pk;
      #pragma unroll
      for (int j = 0; j < 8; ++j) {
        const int o = c0 + j;
        float v = b0s[o];
        #pragma unroll
        for (int c = 0; c < 6; ++c) v = fmaf(u[c], w0s[o*6+c], v);
        v = fmaxf(fmaf(v, sc_s[o], sh_s[o]), 0.f);   // BN1 + ReLU
        pk[j] = (short)f2bf_bits(v);
      }
      *((short8*)&xT[t*XT_STRIDE + c0]) = pk;
    }
  }
  __syncthreads();
  const int lane = t & 63, wv = t >> 6;
  const int qd = lane >> 4, ln = lane & 15;
  short8 A[4][2];
  #pragma unroll
  for (int rt = 0; rt < 4; ++rt) {
    #pragma unroll
    for (int kh = 0; kh < 2; ++kh) {
      const float* wp = w1 + (size_t)(rt*16 + ln)*64 + kh*32 + qd*8;
      float4 f0 = *(const float4*)wp;
      float4 f1 = *(const float4*)(wp + 4);
      short8 a;
      a[0]=(short)f2bf_bits(f0.x); a[1]=(short)f2bf_bits(f0.y);
      a[2]=(short)f2bf_bits(f0.z); a[3]=(short)f2bf_bits(f0.w);
      a[4]=(short)f2bf_bits(f1.x); a[5]=(short)f2bf_bits(f1.y);
      a[6]=(short)f2bf_bits(f1.z); a[7]=(short)f2bf_bits(f1.w);
      A[rt][kh] = a;
    }
  }
  floatx4 acc[4][4];
  #pragma unroll
  for (int rt = 0; rt < 4; ++rt)
    #pragma unroll
    for (int ct = 0; ct < 4; ++ct)
      acc[rt][ct] = (floatx4)0.f;
  #pragma unroll
  for (int ct = 0; ct < 4; ++ct) {
    const int coll = wv*64 + ct*16 + ln;
    short8 B0 = *((const short8*)&xT[coll*XT_STRIDE + qd*8]);
    short8 B1 = *((const short8*)&xT[coll*XT_STRIDE + 32 + qd*8]);
    #pragma unroll
    for (int rt = 0; rt < 4; ++rt) {
      acc[rt][ct] = __builtin_amdgcn_mfma_f32_16x16x32_bf16(A[rt][0], B0, acc[rt][ct], 0,0,0);
      acc[rt][ct] = __builtin_amdgcn_mfma_f32_16x16x32_bf16(A[rt][1], B1, acc[rt][ct], 0,0,0);
    }
  }
  float* dst = accum + (size_t)(blockIdx.x & (NBUCK-1))*128;
  #pragma unroll
  for (int rt = 0; rt < 4; ++rt) {
    float s[4]  = {0.f,0.f,0.f,0.f};
    float sq[4] = {0.f,0.f,0.f,0.f};
    #pragma unroll
    for (int ct = 0; ct < 4; ++ct) {
      const int col = col0 + wv*64 + ct*16 + ln;
      #pragma unroll
      for (int r = 0; r < 4; ++r) {
        const int o = rt*16 + qd*4 + r;
        float v = acc[rt][ct][r] + bias_s[o];
        x2[(size_t)o*NT_COLS + col] = __float2bfloat16(v);
        s[r] += v; sq[r] = fmaf(v, v, sq[r]);
      }
    }
    #pragma unroll
    for (int r = 0; r < 4; ++r) {
      float a = add16_dpp(s[r]);
      float q = add16_dpp(sq[r]);
      if (ln == 15) {
        const int o = rt*16 + qd*4 + r;
        atomicAdd(&dst[o], a);
        atomicAdd(&dst[64 + o], q);
      }
    }
  }
}

// ---------------- Layer 3: MFMA + fused stats + fused max-pool --------------
__global__ __launch_bounds__(256) void k_layer3_mfma(
    const bf16*  __restrict__ xin,   // [64][NT_COLS] = x2
    const float* __restrict__ wN,    // [128][64]
    const float* __restrict__ bN,    // [128]
    const float* __restrict__ scsh,  // sc2[64], sh2[64]
    float*       __restrict__ accum, // [NBUCK][256]
    float*       __restrict__ mx) {  // [128][NT_COLS/NK]
  constexpr int CO = 128, RT = CO/16;
  __shared__ short xT[256*XT_STRIDE];
  __shared__ float sc_s[64], sh_s[64], bias_s[CO];
  const int t = threadIdx.x;
  const int col0 = blockIdx.x * 256;
  if (t < 64) { sc_s[t] = scsh[t]; sh_s[t] = scsh[64+t]; }
  if (t < CO) bias_s[t] = bN[t];
  __syncthreads();
  {
    const int col = col0 + t;
    #pragma unroll
    for (int c0 = 0; c0 < 64; c0 += 8) {
      short8 pk;
      #pragma unroll
      for (int j = 0; j < 8; ++j) {
        float v = __bfloat162float(xin[(size_t)(c0+j)*NT_COLS + col]);
        v = fmaxf(fmaf(v, sc_s[c0+j], sh_s[c0+j]), 0.f);
        pk[j] = (short)f2bf_bits(v);
      }
      *((short8*)&xT[t*XT_STRIDE + c0]) = pk;
    }
  }
  __syncthreads();
  const int lane = t & 63, wv = t >> 6;
  const int qd = lane >> 4, ln = lane & 15;
  short8 A[RT][2];
  #pragma unroll
  for (int rt = 0; rt < RT; ++rt) {
    #pragma unroll
    for (int kh = 0; kh < 2; ++kh) {
      const float* wp = wN + (size_t)(rt*16 + ln)*64 + kh*32 + qd*8;
      float4 f0 = *(const float4*)wp;
      float4 f1 = *(const float4*)(wp + 4);
      short8 a;
      a[0]=(short)f2bf_bits(f0.x); a[1]=(short)f2bf_bits(f0.y);
      a[2]=(short)f2bf_bits(f0.z); a[3]=(short)f2bf_bits(f0.w);
      a[4]=(short)f2bf_bits(f1.x); a[5]=(short)f2bf_bits(f1.y);
      a[6]=(short)f2bf_bits(f1.z); a[7]=(short)f2bf_bits(f1.w);
      A[rt][kh] = a;
    }
  }
  floatx4 acc[RT][4];
  #pragma unroll
  for (int rt = 0; rt < RT; ++rt)
    #pragma unroll
    for (int ct = 0; ct < 4; ++ct)
      acc[rt][ct] = (floatx4)0.f;
  #pragma unroll
  for (int ct = 0; ct < 4; ++ct) {
    const int coll = wv*64 + ct*16 + ln;
    short8 B0 = *((const short8*)&xT[coll*XT_STRIDE + qd*8]);
    short8 B1 = *((const short8*)&xT[coll*XT_STRIDE + 32 + qd*8]);
    #pragma unroll
    for (int rt = 0; rt < RT; ++rt) {
      acc[rt][ct] = __builtin_amdgcn_mfma_f32_16x16x32_bf16(A[rt][0], B0, acc[rt][ct], 0,0,0);
      acc[rt][ct] = __builtin_amdgcn_mfma_f32_16x16x32_bf16(A[rt][1], B1, acc[rt][ct], 0,0,0);
    }
  }
  float* dst = accum + (size_t)(blockIdx.x & (NBUCK-1))*(2*CO);
  const int bs0 = (col0 + wv*64) >> 5;     // wave covers bs0, bs0+1
  #pragma unroll
  for (int rt = 0; rt < RT; ++rt) {
    float s[4]  = {0.f,0.f,0.f,0.f};
    float sq[4] = {0.f,0.f,0.f,0.f};
    float mxv[2][4];
    #pragma unroll
    for (int h = 0; h < 2; ++h)
      #pragma unroll
      for (int r = 0; r < 4; ++r) mxv[h][r] = -3.402823466e38f;
    #pragma unroll
    for (int ct = 0; ct < 4; ++ct) {
      #pragma unroll
      for (int r = 0; r < 4; ++r) {
        const int o = rt*16 + qd*4 + r;
        float v = acc[rt][ct][r] + bias_s[o];
        mxv[ct>>1][r] = fmaxf(mxv[ct>>1][r], v);
        s[r] += v; sq[r] = fmaf(v, v, sq[r]);
      }
    }
    #pragma unroll
    for (int h = 0; h < 2; ++h) {
      #pragma unroll
      for (int r = 0; r < 4; ++r) {
        float m = mxv[h][r];
        m = fmax_dpp<0x111,0xF,0xF>(m);
        m = fmax_dpp<0x112,0xF,0xF>(m);
        m = fmax_dpp<0x114,0xF,0xF>(m);
        m = fmax_dpp<0x118,0xF,0xF>(m);
        if (ln == 15) {
          const int o = rt*16 + qd*4 + r;
          mx[(size_t)o*(NT_COLS/NK) + bs0 + h] = m;
        }
      }
    }
    #pragma unroll
    for (int r = 0; r < 4; ++r) {
      float a = add16_dpp(s[r]);
      float q = add16_dpp(sq[r]);
      if (ln == 15) {
        const int o = rt*16 + qd*4 + r;
        atomicAdd(&dst[o], a);
        atomicAdd(&dst[CO + o], q);
      }
    }
  }
}

// ---------------- final BN+ReLU on pooled maxes (fp32 out) ------------------
__global__ __launch_bounds__(256) void k_bnmax(const float* __restrict__ mx,
                                               const float* __restrict__ scsh,
                                               float* __restrict__ out1) {
  const int blk = blockIdx.x;        // 16 b x 128 o
  const int o = blk & 127;
  const int b = blk >> 7;
  const float sc = scsh[o], sh = scsh[128+o];
  const int s = threadIdx.x * 4;
  float4 v = *(const float4*)(mx + (size_t)o*(NT_COLS/NK) + b*NS + s);
  float4 r;
  r.x = fmaxf(fmaf(v.x, sc, sh), 0.f);
  r.y = fmaxf(fmaf(v.y, sc, sh), 0.f);
  r.z = fmaxf(fmaf(v.z, sc, sh), 0.f);
  r.w = fmaxf(fmaf(v.w, sc, sh), 0.f);
  *(float4*)(out1 + (size_t)(b*128 + o)*NS + s) = r;
}

extern "C" void kernel_launch(void* const* d_in, const int* in_sizes, int n_in,
                              void* d_out, int out_size, void* d_ws, size_t ws_size,
                              hipStream_t stream) {
  const float* xyz  = (const float*)d_in[0];
  const float* feat = (const float*)d_in[1];
  const float* w0 = (const float*)d_in[2];
  const float* b0 = (const float*)d_in[3];
  const float* g0 = (const float*)d_in[4];
  const float* bt0= (const float*)d_in[5];
  const float* w1 = (const float*)d_in[6];
  const float* b1 = (const float*)d_in[7];
  const float* g1 = (const float*)d_in[8];
  const float* bt1= (const float*)d_in[9];
  const float* w2 = (const float*)d_in[10];
  const float* b2 = (const float*)d_in[11];
  const float* g2 = (const float*)d_in[12];
  const float* bt2= (const float*)d_in[13];

  float* out0 = (float*)d_out;                     // (B,3,NS) fp32
  float* out1 = out0 + (size_t)NB*3*NS;            // (B,128,NS) fp32

  // Workspace (max offset ~138 MB; ws >= 194 MB proven):
  //   accum@0 (128KB, zeroed by k_fps prologue: l1-moments NBUCKx32,
  //   l2 @+8192f NBUCKx128, l3 @+16384f NBUCKx256)
  //   scsh@131072 (l1:0, l2:128, l3:256), newxyz@133120, bidx@329728,
  //   x2@2426880 (64MB), mx3@136644608 (8MB fp32)
  char* ws = (char*)d_ws;
  float* accum  = (float*)(ws + 0);
  float* acc_l1 = accum;                 // NBUCK x 32 (27 used: S6 + M21)
  float* acc_l2 = accum + 8192;          // NBUCK x 128
  float* acc_l3 = accum + 16384;         // NBUCK x 256
  float* scsh   = (float*)(ws + 131072);
  float* newxyz = (float*)(ws + 133120);
  int*   bidx   = (int*)  (ws + 329728);
  bf16*  x2     = (bf16*) (ws + 2426880);
  float* mx3    = (float*)(ws + 136644608);

  k_fps  <<<NB, 256, 0, stream>>>(xyz, newxyz, out0, accum);
  k_ballq<<<NB*256, 256, 0, stream>>>(xyz, newxyz, bidx);

  k_moments  <<<256, 256, 0, stream>>>(xyz, feat, newxyz, bidx, acc_l1);
  k_finalize1<<<1,    64, 0, stream>>>(acc_l1, w0, b0, g0, bt0, scsh + 0);

  k_layer2_mfma<<<NT_COLS/256, 256, 0, stream>>>(xyz, feat, newxyz, bidx,
                                                 w0, b0, w1, b1, scsh + 0,
                                                 acc_l2, x2);
  k_finalize<<<1, 256, 0, stream>>>(acc_l2, g1, bt1, scsh + 128, 64);

  k_layer3_mfma<<<NT_COLS/256, 256, 0, stream>>>(x2, w2, b2, scsh + 128,
                                                 acc_l3, mx3);
  k_finalize<<<1, 256, 0, stream>>>(acc_l3, g2, bt2, scsh + 256, 128);

  k_bnmax <<<NB*128, 256, 0, stream>>>(mx3, scsh + 256, out1);
}

// Round 15
// 819.019 us; speedup vs baseline: 1.3897x; 1.0220x over previous
//
#include <hip/hip_runtime.h>
#include <hip/hip_bf16.h>
#include <stdint.h>

#define NB 16
#define NPTS 4096
#define NS 1024
#define NK 32
#define NT_COLS (NB*NS*NK)   // 524288 columns (b*NS+s)*NK + k
#define NBUCK 64             // stat-accumulator buckets

typedef __hip_bfloat16 bf16;
typedef __attribute__((ext_vector_type(8))) short short8;   // 8 bf16 (4 VGPRs)
typedef __attribute__((ext_vector_type(4))) float floatx4;  // MFMA C/D
typedef __attribute__((ext_vector_type(2))) float f32x2;    // pk-fp32 pair

__device__ __forceinline__ unsigned short f2bf_bits(float v) {
  bf16 b = __float2bfloat16(v);
  return *(unsigned short*)&b;
}

// DPP-shifted fmax (verified gfx950 R5/R7/R8). Inactive/OOB src lanes keep old=x.
template<int CTRL, int RM, int BM>
__device__ __forceinline__ float fmax_dpp(float x) {
  int o = __builtin_amdgcn_update_dpp(__float_as_int(x), __float_as_int(x),
                                      CTRL, RM, BM, false);
  return fmaxf(x, __int_as_float(o));
}
// DPP add with zero-fill identity; RM-masked rows add 0 (old=0).
template<int CTRL, int RM>
__device__ __forceinline__ float add_dpp(float x) {
  int o = __builtin_amdgcn_update_dpp(0, __float_as_int(x), CTRL, RM, 0xF, true);
  return __fadd_rn(x, __int_as_float(o));
}
// 16-lane row sum -> lane 15 of each row (mfma C-layout stats).
__device__ __forceinline__ float add16_dpp(float x) {
  x = add_dpp<0x111,0xF>(x); x = add_dpp<0x112,0xF>(x);
  x = add_dpp<0x114,0xF>(x); x = add_dpp<0x118,0xF>(x);
  return x;
}
// full wave64 sum -> lane 63.
__device__ __forceinline__ float add64_dpp(float x) {
  x = add_dpp<0x111,0xF>(x); x = add_dpp<0x112,0xF>(x);
  x = add_dpp<0x114,0xF>(x); x = add_dpp<0x118,0xF>(x);
  x = add_dpp<0x142,0xA>(x);   // row_bcast:15 -> rows 1,3
  x = add_dpp<0x143,0xC>(x);   // row_bcast:31 -> rows 2,3
  return x;
}

// ---------------- FPS: R8 structure + source-level pk-f32 dist loop ---------
// np-exact: per-point (x-c)^2 elementwise and sequential 3-term sum, no FMA
// (contract(off) blocks fma contraction; vector +,* are per-half IEEE-rn ==
// __fadd_rn/__fmul_rn; x+(-c) == x-c exactly). First-occurrence argmax:
// in-lane ascending strict >, in-wave lowest lane via ctz(ballot), cross-wave
// strict > in ascending wave order — identical to R14 (passed, absmax
// 0.078125). ONLY delta vs R14: dist arithmetic expressed on float2 vectors
// so the compiler can form v_pk_add_f32/v_pk_mul_f32 (halves dist-loop issue;
// R10's failed pk attempt used inline asm whose scheduling barriers caused
// the regression — source-level vectors avoid that; worst case scalarizes to
// exactly the R14 code).
__global__ __launch_bounds__(256) void k_fps(const float* __restrict__ xyz,
                                             float* __restrict__ newxyz,
                                             float* __restrict__ out0,
                                             float* __restrict__ zero_region) {
  const int b = blockIdx.x;
  const int t = threadIdx.x;
  {
    float* zp = zero_region + (size_t)b*2048 + t;
    #pragma unroll
    for (int j = 0; j < 8; ++j) zp[j*256] = 0.f;
  }
  __shared__ float xs[NPTS], ys[NPTS], zs[NPTS];
  __shared__ float selx[NS], sely[NS], selz[NS];
  __shared__ float2 pair[2][4];   // double-buffered (value, idx-bits) per wave
  const float* p = xyz + (size_t)b * 3 * NPTS;
  for (int i = t; i < NPTS; i += 256) {
    xs[i] = p[i];
    ys[i] = p[NPTS + i];
    zs[i] = p[2*NPTS + i];
  }
  __syncthreads();
  f32x2 px[8], py[8], pz[8];
  float dist[16];
  const int p0 = t * 16;
  #pragma unroll
  for (int j2 = 0; j2 < 8; ++j2) {
    px[j2] = (f32x2){xs[p0+2*j2], xs[p0+2*j2+1]};
    py[j2] = (f32x2){ys[p0+2*j2], ys[p0+2*j2+1]};
    pz[j2] = (f32x2){zs[p0+2*j2], zs[p0+2*j2+1]};
    dist[2*j2] = 1e10f; dist[2*j2+1] = 1e10f;
  }
  const int lane = t & 63, wv = t >> 6;
  int cur = 0;
  for (int i = 0; i < NS; ++i) {
    float cx = xs[cur], cy = ys[cur], cz = zs[cur];
    if (t == 0) { selx[i] = cx; sely[i] = cy; selz[i] = cz; }
    if (i == NS-1) break;
    const f32x2 ncx = (f32x2){-cx, -cx};   // exact sign flips
    const f32x2 ncy = (f32x2){-cy, -cy};
    const f32x2 ncz = (f32x2){-cz, -cz};
    float bv = -1.0f; int bi = p0;
    #pragma unroll
    for (int j2 = 0; j2 < 8; ++j2) {
      f32x2 d;
      {
        #pragma clang fp contract(off)
        f32x2 dx = px[j2] + ncx;           // == __fsub_rn(px, cx) per half
        f32x2 dy = py[j2] + ncy;
        f32x2 dz = pz[j2] + ncz;
        d = dx*dx + dy*dy + dz*dz;         // ((x2+y2)+z2), rn, no fma
      }
      float nd0 = fminf(dist[2*j2],   d.x);
      float nd1 = fminf(dist[2*j2+1], d.y);
      dist[2*j2] = nd0; dist[2*j2+1] = nd1;
      if (nd0 > bv) { bv = nd0; bi = p0 + 2*j2; }     // strict > => first occ.
      if (nd1 > bv) { bv = nd1; bi = p0 + 2*j2 + 1; }
    }
    float x = bv;
    x = fmax_dpp<0x111,0xF,0xF>(x);   // row_shr:1
    x = fmax_dpp<0x112,0xF,0xF>(x);   // row_shr:2
    x = fmax_dpp<0x114,0xF,0xF>(x);   // row_shr:4
    x = fmax_dpp<0x118,0xF,0xF>(x);   // row_shr:8
    x = fmax_dpp<0x142,0xA,0xF>(x);   // row_bcast:15 -> rows 1,3
    x = fmax_dpp<0x143,0xC,0xF>(x);   // row_bcast:31 -> rows 2,3
    float M = __int_as_float(__builtin_amdgcn_readlane(__float_as_int(x), 63));
    unsigned long long mk = __ballot(bv == M);
    int sl  = (int)__builtin_ctzll(mk);
    int wbi = __builtin_amdgcn_readlane(bi, sl);
    if ((t & 63) == 0) pair[i & 1][wv] = make_float2(M, __int_as_float(wbi));
    __syncthreads();
    const float4* pb = (const float4*)&pair[i & 1][0];
    float4 q01 = pb[0], q23 = pb[1];
    float bestv = q01.x; int besti = __float_as_int(q01.y);
    if (q01.z > bestv) { bestv = q01.z; besti = __float_as_int(q01.w); }
    if (q23.x > bestv) { bestv = q23.x; besti = __float_as_int(q23.y); }
    if (q23.z > bestv) { bestv = q23.z; besti = __float_as_int(q23.w); }
    cur = besti;
  }
  __syncthreads();
  for (int i = t; i < NS; i += 256) {
    float vx = selx[i], vy = sely[i], vz = selz[i];
    size_t q = (size_t)b*3*NS + i;
    out0[q] = vx; out0[q + NS] = vy; out0[q + 2*NS] = vz;   // bit-exact copies
    size_t o = (size_t)(b*NS + i)*3;
    newxyz[o] = vx; newxyz[o+1] = vy; newxyz[o+2] = vz;
  }
}

// ---------------- Ball query: LDS-staged points, 4 queries/block ------------
__global__ __launch_bounds__(256) void k_ballq(const float* __restrict__ xyz,
                                               const float* __restrict__ newxyz,
                                               int* __restrict__ idx) {
  __shared__ float xs[NPTS], ys[NPTS], zs[NPTS];
  const int b  = blockIdx.x >> 8;                 // 256 blocks per batch
  const int s  = (blockIdx.x & 255) * 4 + (threadIdx.x >> 6);
  const int lane = threadIdx.x & 63;
  const float* p = xyz + (size_t)b * 3 * NPTS;
  for (int i = threadIdx.x; i < NPTS; i += 256) {
    xs[i] = p[i];
    ys[i] = p[NPTS + i];
    zs[i] = p[2*NPTS + i];
  }
  __syncthreads();
  const size_t nq = (size_t)(b*NS + s)*3;
  const float nx = newxyz[nq], ny = newxyz[nq+1], nz = newxyz[nq+2];
  const float sn = __fadd_rn(__fadd_rn(__fmul_rn(nx,nx), __fmul_rn(ny,ny)), __fmul_rn(nz,nz));
  const float R2 = (float)(0.2*0.2);
  int* out = idx + (size_t)(b*NS + s) * NK;
  int cnt = 0, first = 0;
  for (int c0 = 0; c0 < NPTS; c0 += 64) {
    int n = c0 + lane;
    float x = xs[n], y = ys[n], z = zs[n];
    float sx = __fadd_rn(__fadd_rn(__fmul_rn(x,x), __fmul_rn(y,y)), __fmul_rn(z,z));
    float dt = __fadd_rn(__fadd_rn(__fmul_rn(nx,x), __fmul_rn(ny,y)), __fmul_rn(nz,z));
    float sqr = __fsub_rn(__fadd_rn(sn, sx), __fmul_rn(2.0f, dt));
    bool inr = (sqr <= R2);
    unsigned long long m = __ballot(inr);
    if (m != 0ull) {
      if (cnt == 0) first = c0 + (int)__builtin_ctzll(m);
      int rank = __popcll(m & ((1ull << lane) - 1ull));
      int pos = cnt + rank;
      if (inr && pos < NK) out[pos] = n;
      cnt += __popcll(m);
      if (cnt >= NK) break;
    }
  }
  int tot = cnt < NK ? cnt : NK;
  if (lane >= tot && lane < NK) out[lane] = first;
}

// ---------------- Moments: S = sum u (6), M = sum u u^T (21) ----------------
// Layer-1 stats are LINEAR in the gathered input u (no relu before BN).
// R13 post-mortem: do NOT fuse finalizes into producers (ticket race +
// cross-XCD visibility). Separate finalize kernels are the proven form.
__global__ __launch_bounds__(256) void k_moments(const float* __restrict__ xyz,
                                                 const float* __restrict__ feat,
                                                 const float* __restrict__ newxyz,
                                                 const int* __restrict__ idx,
                                                 float* __restrict__ accum) {
  const int t = threadIdx.x;
  float S[6] = {0,0,0,0,0,0};
  float Mm[21];
  #pragma unroll
  for (int k = 0; k < 21; ++k) Mm[k] = 0.f;
  for (int it = 0; it < 8; ++it) {
    const int col = blockIdx.x*2048 + it*256 + t;
    const int bs = col >> 5;
    const int b  = bs >> 10;
    const int n  = idx[col];
    const float* xb = xyz  + (size_t)b*3*NPTS;
    const float* fb = feat + (size_t)b*3*NPTS;
    float u[6];
    u[0] = __fsub_rn(xb[n],        newxyz[(size_t)bs*3]);
    u[1] = __fsub_rn(xb[NPTS+n],   newxyz[(size_t)bs*3+1]);
    u[2] = __fsub_rn(xb[2*NPTS+n], newxyz[(size_t)bs*3+2]);
    u[3] = fb[n];
    u[4] = fb[NPTS+n];
    u[5] = fb[2*NPTS+n];
    int k = 0;
    #pragma unroll
    for (int i = 0; i < 6; ++i) {
      S[i] += u[i];
      #pragma unroll
      for (int j = i; j < 6; ++j) { Mm[k] = fmaf(u[i], u[j], Mm[k]); ++k; }
    }
  }
  const int lane = t & 63;
  float* dst = accum + (size_t)(blockIdx.x & (NBUCK-1))*32;   // 27 used of 32
  #pragma unroll
  for (int i = 0; i < 6; ++i) {
    float s = add64_dpp(S[i]);
    if (lane == 63) atomicAdd(&dst[i], s);
  }
  #pragma unroll
  for (int k = 0; k < 21; ++k) {
    float m = add64_dpp(Mm[k]);
    if (lane == 63) atomicAdd(&dst[6+k], m);
  }
}

// ---------------- finalize layer-1 BN from moments (closed form) ------------
__global__ void k_finalize1(const float* __restrict__ accum,
                            const float* __restrict__ w0, const float* __restrict__ b0,
                            const float* __restrict__ g, const float* __restrict__ beta,
                            float* __restrict__ scsh) {
  __shared__ float Sm[27];
  const int t = threadIdx.x;
  if (t < 27) {
    float s = 0.f;
    for (int bkt = 0; bkt < NBUCK; ++bkt) s += accum[(size_t)bkt*32 + t];
    Sm[t] = s;
  }
  __syncthreads();
  if (t < 64) {
    const float* w = w0 + t*6;
    const float b = b0[t];
    float ws = 0.f;
    #pragma unroll
    for (int i = 0; i < 6; ++i) ws = fmaf(w[i], Sm[i], ws);
    float quad = 0.f;
    int k = 6;
    #pragma unroll
    for (int i = 0; i < 6; ++i) {
      #pragma unroll
      for (int j = i; j < 6; ++j) {
        float c = w[i]*w[j];
        if (j > i) c *= 2.f;
        quad = fmaf(c, Sm[k], quad);
        ++k;
      }
    }
    const float n = (float)NT_COLS;
    float mean = (ws + n*b) / n;
    float ex2  = (quad + 2.f*b*ws + n*b*b) / n;
    float var  = ex2 - mean*mean;
    if (var < 0.f) var = 0.f;
    float rs = rsqrtf(var + 1e-5f);
    float sc = g[t] * rs;
    scsh[t]    = sc;
    scsh[64+t] = beta[t] - mean * sc;
  }
}

// ---------------- generic bucket finalize (layers 2/3) ----------------------
__global__ void k_finalize(const float* __restrict__ accum,
                           const float* __restrict__ g, const float* __restrict__ beta,
                           float* __restrict__ scsh, int C) {
  int o = threadIdx.x;
  if (o < C) {
    float s = 0.f, ss = 0.f;
    for (int bkt = 0; bkt < NBUCK; ++bkt) {
      s  += accum[(size_t)bkt*(2*C) + o];
      ss += accum[(size_t)bkt*(2*C) + C + o];
    }
    const float n = (float)NT_COLS;
    float mu  = s / n;
    float var = ss / n - mu*mu;
    if (var < 0.f) var = 0.f;
    float rs = rsqrtf(var + 1e-5f);
    float sc = g[o] * rs;
    scsh[o]   = sc;
    scsh[C+o] = beta[o] - mu * sc;
  }
}

#define XT_STRIDE 72   // bf16 elems; 144 B row -> b128-aligned

// ---------------- Layer 2: recompute-x1 staging + MFMA + fused stats --------
__global__ __launch_bounds__(256) void k_layer2_mfma(
    const float* __restrict__ xyz,
    const float* __restrict__ feat,
    const float* __restrict__ newxyz,
    const int*   __restrict__ idx,
    const float* __restrict__ w0g,   // [64][6]
    const float* __restrict__ b0g,   // [64]
    const float* __restrict__ w1,    // [64][64]
    const float* __restrict__ b1,    // [64]
    const float* __restrict__ scsh,  // sc1[64], sh1[64]
    float*       __restrict__ accum, // [NBUCK][128]
    bf16*        __restrict__ x2) {  // [64][NT_COLS]
  __shared__ short xT[256*XT_STRIDE];
  __shared__ float w0s[64*6];
  __shared__ float b0s[64];
  __shared__ float sc_s[64], sh_s[64], bias_s[64];
  const int t = threadIdx.x;
  const int col0 = blockIdx.x * 256;
  for (int i = t; i < 64*6; i += 256) w0s[i] = w0g[i];
  if (t < 64) {
    b0s[t] = b0g[t];
    sc_s[t] = scsh[t]; sh_s[t] = scsh[64+t];
    bias_s[t] = b1[t];
  }
  __syncthreads();
  {
    const int col = col0 + t;
    const int bs = col >> 5;
    const int b  = bs >> 10;
    const int n  = idx[col];
    const float* xb = xyz  + (size_t)b*3*NPTS;
    const float* fb = feat + (size_t)b*3*NPTS;
    float u[6];
    u[0] = __fsub_rn(xb[n],        newxyz[(size_t)bs*3]);
    u[1] = __fsub_rn(xb[NPTS+n],   newxyz[(size_t)bs*3+1]);
    u[2] = __fsub_rn(xb[2*NPTS+n], newxyz[(size_t)bs*3+2]);
    u[3] = fb[n];
    u[4] = fb[NPTS+n];
    u[5] = fb[2*NPTS+n];
    #pragma unroll
    for (int c0 = 0; c0 < 64; c0 += 8) {
      short8 pk;
      #pragma unroll
      for (int j = 0; j < 8; ++j) {
        const int o = c0 + j;
        float v = b0s[o];
        #pragma unroll
        for (int c = 0; c < 6; ++c) v = fmaf(u[c], w0s[o*6+c], v);
        v = fmaxf(fmaf(v, sc_s[o], sh_s[o]), 0.f);   // BN1 + ReLU
        pk[j] = (short)f2bf_bits(v);
      }
      *((short8*)&xT[t*XT_STRIDE + c0]) = pk;
    }
  }
  __syncthreads();
  const int lane = t & 63, wv = t >> 6;
  const int qd = lane >> 4, ln = lane & 15;
  short8 A[4][2];
  #pragma unroll
  for (int rt = 0; rt < 4; ++rt) {
    #pragma unroll
    for (int kh = 0; kh < 2; ++kh) {
      const float* wp = w1 + (size_t)(rt*16 + ln)*64 + kh*32 + qd*8;
      float4 f0 = *(const float4*)wp;
      float4 f1 = *(const float4*)(wp + 4);
      short8 a;
      a[0]=(short)f2bf_bits(f0.x); a[1]=(short)f2bf_bits(f0.y);
      a[2]=(short)f2bf_bits(f0.z); a[3]=(short)f2bf_bits(f0.w);
      a[4]=(short)f2bf_bits(f1.x); a[5]=(short)f2bf_bits(f1.y);
      a[6]=(short)f2bf_bits(f1.z); a[7]=(short)f2bf_bits(f1.w);
      A[rt][kh] = a;
    }
  }
  floatx4 acc[4][4];
  #pragma unroll
  for (int rt = 0; rt < 4; ++rt)
    #pragma unroll
    for (int ct = 0; ct < 4; ++ct)
      acc[rt][ct] = (floatx4)0.f;
  #pragma unroll
  for (int ct = 0; ct < 4; ++ct) {
    const int coll = wv*64 + ct*16 + ln;
    short8 B0 = *((const short8*)&xT[coll*XT_STRIDE + qd*8]);
    short8 B1 = *((const short8*)&xT[coll*XT_STRIDE + 32 + qd*8]);
    #pragma unroll
    for (int rt = 0; rt < 4; ++rt) {
      acc[rt][ct] = __builtin_amdgcn_mfma_f32_16x16x32_bf16(A[rt][0], B0, acc[rt][ct], 0,0,0);
      acc[rt][ct] = __builtin_amdgcn_mfma_f32_16x16x32_bf16(A[rt][1], B1, acc[rt][ct], 0,0,0);
    }
  }
  float* dst = accum + (size_t)(blockIdx.x & (NBUCK-1))*128;
  #pragma unroll
  for (int rt = 0; rt < 4; ++rt) {
    float s[4]  = {0.f,0.f,0.f,0.f};
    float sq[4] = {0.f,0.f,0.f,0.f};
    #pragma unroll
    for (int ct = 0; ct < 4; ++ct) {
      const int col = col0 + wv*64 + ct*16 + ln;
      #pragma unroll
      for (int r = 0; r < 4; ++r) {
        const int o = rt*16 + qd*4 + r;
        float v = acc[rt][ct][r] + bias_s[o];
        x2[(size_t)o*NT_COLS + col] = __float2bfloat16(v);
        s[r] += v; sq[r] = fmaf(v, v, sq[r]);
      }
    }
    #pragma unroll
    for (int r = 0; r < 4; ++r) {
      float a = add16_dpp(s[r]);
      float q = add16_dpp(sq[r]);
      if (ln == 15) {
        const int o = rt*16 + qd*4 + r;
        atomicAdd(&dst[o], a);
        atomicAdd(&dst[64 + o], q);
      }
    }
  }
}

// ---------------- Layer 3: MFMA + fused stats + fused max-pool --------------
__global__ __launch_bounds__(256) void k_layer3_mfma(
    const bf16*  __restrict__ xin,   // [64][NT_COLS] = x2
    const float* __restrict__ wN,    // [128][64]
    const float* __restrict__ bN,    // [128]
    const float* __restrict__ scsh,  // sc2[64], sh2[64]
    float*       __restrict__ accum, // [NBUCK][256]
    float*       __restrict__ mx) {  // [128][NT_COLS/NK]
  constexpr int CO = 128, RT = CO/16;
  __shared__ short xT[256*XT_STRIDE];
  __shared__ float sc_s[64], sh_s[64], bias_s[CO];
  const int t = threadIdx.x;
  const int col0 = blockIdx.x * 256;
  if (t < 64) { sc_s[t] = scsh[t]; sh_s[t] = scsh[64+t]; }
  if (t < CO) bias_s[t] = bN[t];
  __syncthreads();
  {
    const int col = col0 + t;
    #pragma unroll
    for (int c0 = 0; c0 < 64; c0 += 8) {
      short8 pk;
      #pragma unroll
      for (int j = 0; j < 8; ++j) {
        float v = __bfloat162float(xin[(size_t)(c0+j)*NT_COLS + col]);
        v = fmaxf(fmaf(v, sc_s[c0+j], sh_s[c0+j]), 0.f);
        pk[j] = (short)f2bf_bits(v);
      }
      *((short8*)&xT[t*XT_STRIDE + c0]) = pk;
    }
  }
  __syncthreads();
  const int lane = t & 63, wv = t >> 6;
  const int qd = lane >> 4, ln = lane & 15;
  short8 A[RT][2];
  #pragma unroll
  for (int rt = 0; rt < RT; ++rt) {
    #pragma unroll
    for (int kh = 0; kh < 2; ++kh) {
      const float* wp = wN + (size_t)(rt*16 + ln)*64 + kh*32 + qd*8;
      float4 f0 = *(const float4*)wp;
      float4 f1 = *(const float4*)(wp + 4);
      short8 a;
      a[0]=(short)f2bf_bits(f0.x); a[1]=(short)f2bf_bits(f0.y);
      a[2]=(short)f2bf_bits(f0.z); a[3]=(short)f2bf_bits(f0.w);
      a[4]=(short)f2bf_bits(f1.x); a[5]=(short)f2bf_bits(f1.y);
      a[6]=(short)f2bf_bits(f1.z); a[7]=(short)f2bf_bits(f1.w);
      A[rt][kh] = a;
    }
  }
  floatx4 acc[RT][4];
  #pragma unroll
  for (int rt = 0; rt < RT; ++rt)
    #pragma unroll
    for (int ct = 0; ct < 4; ++ct)
      acc[rt][ct] = (floatx4)0.f;
  #pragma unroll
  for (int ct = 0; ct < 4; ++ct) {
    const int coll = wv*64 + ct*16 + ln;
    short8 B0 = *((const short8*)&xT[coll*XT_STRIDE + qd*8]);
    short8 B1 = *((const short8*)&xT[coll*XT_STRIDE + 32 + qd*8]);
    #pragma unroll
    for (int rt = 0; rt < RT; ++rt) {
      acc[rt][ct] = __builtin_amdgcn_mfma_f32_16x16x32_bf16(A[rt][0], B0, acc[rt][ct], 0,0,0);
      acc[rt][ct] = __builtin_amdgcn_mfma_f32_16x16x32_bf16(A[rt][1], B1, acc[rt][ct], 0,0,0);
    }
  }
  float* dst = accum + (size_t)(blockIdx.x & (NBUCK-1))*(2*CO);
  const int bs0 = (col0 + wv*64) >> 5;     // wave covers bs0, bs0+1
  #pragma unroll
  for (int rt = 0; rt < RT; ++rt) {
    float s[4]  = {0.f,0.f,0.f,0.f};
    float sq[4] = {0.f,0.f,0.f,0.f};
    float mxv[2][4];
    #pragma unroll
    for (int h = 0; h < 2; ++h)
      #pragma unroll
      for (int r = 0; r < 4; ++r) mxv[h][r] = -3.402823466e38f;
    #pragma unroll
    for (int ct = 0; ct < 4; ++ct) {
      #pragma unroll
      for (int r = 0; r < 4; ++r) {
        const int o = rt*16 + qd*4 + r;
        float v = acc[rt][ct][r] + bias_s[o];
        mxv[ct>>1][r] = fmaxf(mxv[ct>>1][r], v);
        s[r] += v; sq[r] = fmaf(v, v, sq[r]);
      }
    }
    #pragma unroll
    for (int h = 0; h < 2; ++h) {
      #pragma unroll
      for (int r = 0; r < 4; ++r) {
        float m = mxv[h][r];
        m = fmax_dpp<0x111,0xF,0xF>(m);
        m = fmax_dpp<0x112,0xF,0xF>(m);
        m = fmax_dpp<0x114,0xF,0xF>(m);
        m = fmax_dpp<0x118,0xF,0xF>(m);
        if (ln == 15) {
          const int o = rt*16 + qd*4 + r;
          mx[(size_t)o*(NT_COLS/NK) + bs0 + h] = m;
        }
      }
    }
    #pragma unroll
    for (int r = 0; r < 4; ++r) {
      float a = add16_dpp(s[r]);
      float q = add16_dpp(sq[r]);
      if (ln == 15) {
        const int o = rt*16 + qd*4 + r;
        atomicAdd(&dst[o], a);
        atomicAdd(&dst[CO + o], q);
      }
    }
  }
}

// ---------------- final BN+ReLU on pooled maxes (fp32 out) ------------------
__global__ __launch_bounds__(256) void k_bnmax(const float* __restrict__ mx,
                                               const float* __restrict__ scsh,
                                               float* __restrict__ out1) {
  const int blk = blockIdx.x;        // 16 b x 128 o
  const int o = blk & 127;
  const int b = blk >> 7;
  const float sc = scsh[o], sh = scsh[128+o];
  const int s = threadIdx.x * 4;
  float4 v = *(const float4*)(mx + (size_t)o*(NT_COLS/NK) + b*NS + s);
  float4 r;
  r.x = fmaxf(fmaf(v.x, sc, sh), 0.f);
  r.y = fmaxf(fmaf(v.y, sc, sh), 0.f);
  r.z = fmaxf(fmaf(v.z, sc, sh), 0.f);
  r.w = fmaxf(fmaf(v.w, sc, sh), 0.f);
  *(float4*)(out1 + (size_t)(b*128 + o)*NS + s) = r;
}

extern "C" void kernel_launch(void* const* d_in, const int* in_sizes, int n_in,
                              void* d_out, int out_size, void* d_ws, size_t ws_size,
                              hipStream_t stream) {
  const float* xyz  = (const float*)d_in[0];
  const float* feat = (const float*)d_in[1];
  const float* w0 = (const float*)d_in[2];
  const float* b0 = (const float*)d_in[3];
  const float* g0 = (const float*)d_in[4];
  const float* bt0= (const float*)d_in[5];
  const float* w1 = (const float*)d_in[6];
  const float* b1 = (const float*)d_in[7];
  const float* g1 = (const float*)d_in[8];
  const float* bt1= (const float*)d_in[9];
  const float* w2 = (const float*)d_in[10];
  const float* b2 = (const float*)d_in[11];
  const float* g2 = (const float*)d_in[12];
  const float* bt2= (const float*)d_in[13];

  float* out0 = (float*)d_out;                     // (B,3,NS) fp32
  float* out1 = out0 + (size_t)NB*3*NS;            // (B,128,NS) fp32

  // Workspace (max offset ~138 MB; ws >= 194 MB proven):
  //   accum@0 (128KB, zeroed by k_fps prologue), scsh@131072,
  //   newxyz@133120, bidx@329728, x2@2426880 (64MB), mx3@136644608 (8MB)
  char* ws = (char*)d_ws;
  float* accum  = (float*)(ws + 0);
  float* acc_l1 = accum;                 // NBUCK x 32 (27 used: S6 + M21)
  float* acc_l2 = accum + 8192;          // NBUCK x 128
  float* acc_l3 = accum + 16384;         // NBUCK x 256
  float* scsh   = (float*)(ws + 131072);
  float* newxyz = (float*)(ws + 133120);
  int*   bidx   = (int*)  (ws + 329728);
  bf16*  x2     = (bf16*) (ws + 2426880);
  float* mx3    = (float*)(ws + 136644608);

  k_fps  <<<NB, 256, 0, stream>>>(xyz, newxyz, out0, accum);
  k_ballq<<<NB*256, 256, 0, stream>>>(xyz, newxyz, bidx);

  k_moments  <<<256, 256, 0, stream>>>(xyz, feat, newxyz, bidx, acc_l1);
  k_finalize1<<<1,    64, 0, stream>>>(acc_l1, w0, b0, g0, bt0, scsh + 0);

  k_layer2_mfma<<<NT_COLS/256, 256, 0, stream>>>(xyz, feat, newxyz, bidx,
                                                 w0, b0, w1, b1, scsh + 0,
                                                 acc_l2, x2);
  k_finalize<<<1, 256, 0, stream>>>(acc_l2, g1, bt1, scsh + 128, 64);

  k_layer3_mfma<<<NT_COLS/256, 256, 0, stream>>>(x2, w2, b2, scsh + 128,
                                                 acc_l3, mx3);
  k_finalize<<<1, 256, 0, stream>>>(acc_l3, g2, bt2, scsh + 256, 128);

  k_bnmax <<<NB*128, 256, 0, stream>>>(mx3, scsh + 256, out1);
}